// Round 5
// baseline (412.324 us; speedup 1.0000x reference)
//
#include <hip/hip_runtime.h>
#include <math.h>

// ---------------------------------------------------------------------------
// Attention: B=4, S=2048, E=1024, H=8, O=128 (fp32 in/out)
// Split-bf16 (hi+lo) MFMA for x->QK and QK^T (precision-critical), plain bf16
// for V / PV / ctx@Wo. Flash-attention (no S x S materialize).
// R1-R5: see history. R6: 2-barrier attn (369.8us total).
// R7/R8: barrier-free attn REGRESSED (latency-bound at 2 waves/SIMD).
// R9: R6 + setprio: attn 168.7us (Mfma 36/VALU 31/Occ 20.6).
// R10: dbuf+raw-barrier NEUTRAL (172.5us, same counters) -> stall is NOT
//     load latency. Recalibrated: one 16x16x32 MFMA = ~19.4 SIMD-cycles;
//     2 waves/SIMD x 132 MFMA/iter = exactly the observed 40% ceiling.
//     Kernel is OCCUPANCY-bound: 2 waves/SIMD can't cover their own
//     softmax phases.
// R11 (this round): 4x resident blocks. BM 128->64 (4 waves x 16 rows),
//     BN 64->32, grid (32,32)=1024 blocks; LDS 67.5->29.1 KB -> 4+
//     blocks/CU; launch_bounds(256,4). Defer-max (T13, THR=8) bundled to
//     offset the doubled per-tile softmax overhead. Skeleton unchanged
//     (2 __syncthreads, single buffer, setprio).
// ---------------------------------------------------------------------------

typedef __attribute__((ext_vector_type(8))) short bf16x8;   // 8 bf16 (4 VGPRs)
typedef __attribute__((ext_vector_type(4))) float f32x4;

#define MFMA(a, b, c) __builtin_amdgcn_mfma_f32_16x16x32_bf16((a), (b), (c), 0, 0, 0)
#define GLB(p) ((const __attribute__((address_space(1))) void*)(p))
#define LDS(p) ((__attribute__((address_space(3))) void*)(p))

#if __has_builtin(__builtin_amdgcn_exp2f)
#define EXP2F(x) __builtin_amdgcn_exp2f(x)
#else
#define EXP2F(x) exp2f(x)
#endif

__device__ __forceinline__ short f2bf(float f) {
    union { float f; unsigned u; } v; v.f = f;
    unsigned r = v.u + 0x7fffu + ((v.u >> 16) & 1u);   // RNE
    return (short)(r >> 16);
}
__device__ __forceinline__ float bf2f(short s) {
    union { unsigned u; float f; } v; v.u = ((unsigned)(unsigned short)s) << 16;
    return v.f;
}

// ---------------- prep kernels ----------------

__global__ __launch_bounds__(256) void split_kernel(
    const float* __restrict__ x, short* __restrict__ hi, short* __restrict__ lo, int n) {
    for (int i = blockIdx.x * blockDim.x + threadIdx.x; i < n; i += gridDim.x * blockDim.x) {
        float f = x[i];
        short h = f2bf(f);
        hi[i] = h;
        lo[i] = f2bf(f - bf2f(h));
    }
}

__global__ __launch_bounds__(256) void build_wt(
    const float* __restrict__ Wq, const float* __restrict__ Wk, const float* __restrict__ Wv,
    short* __restrict__ wth, short* __restrict__ wtl) {
    const int total = 1280 * 1024;
    for (int idx = blockIdx.x * blockDim.x + threadIdx.x; idx < total; idx += gridDim.x * blockDim.x) {
        int n = idx >> 10, k = idx & 1023;
        float f;
        if (n < 1024)      f = Wq[((size_t)(n >> 7) * 1024 + k) * 128 + (n & 127)];
        else if (n < 1152) f = Wk[(size_t)k * 128 + (n - 1024)];
        else               f = Wv[(size_t)k * 128 + (n - 1152)];
        short h = f2bf(f);
        wth[idx] = h;
        wtl[idx] = f2bf(f - bf2f(h));
    }
}

__global__ __launch_bounds__(256) void build_wot(
    const float* __restrict__ Wo, short* __restrict__ wot) {
    const int total = 1024 * 1024;
    for (int idx = blockIdx.x * blockDim.x + threadIdx.x; idx < total; idx += gridDim.x * blockDim.x) {
        int e = idx >> 10, k = idx & 1023;
        wot[idx] = f2bf(Wo[(size_t)k * 1024 + e]);
    }
}

// ---------------- GEMM: C(M x N) = A(M x 1024) @ Bt(N x 1024)^T ----------------
// K-tiles and epilogue staging share one LDS allocation (disjoint lifetimes,
// barrier-separated): 33.8 KB -> 4 blocks/CU.
template <int MODE>
__global__ __launch_bounds__(256, 4) void gemm_k(
    const short* __restrict__ Ah, const short* __restrict__ Al,
    const short* __restrict__ Bth, const short* __restrict__ Btl,
    short* __restrict__ qh, short* __restrict__ ql,
    short* __restrict__ kh, short* __restrict__ kl,
    short* __restrict__ vt, float* __restrict__ outf) {
    constexpr int K = 1024;
    __shared__ __align__(16) char smem[33792];
    short* As_h = (short*)smem;                 // 128x32 = 8192 B
    short* Bs_h = (short*)(smem + 8192);
    short* As_l = (short*)(smem + 16384);       // MODE 0 only
    short* Bs_l = (short*)(smem + 24576);
    unsigned* Ep = (unsigned*)smem;             // 64x132 u32 = 33792 B (epilogue)

    const int t = threadIdx.x;
    const int m0 = blockIdx.x * 128, n0 = blockIdx.y * 128;
    const int wave = t >> 6, lane = t & 63;
    const int wr = wave >> 1, wc = wave & 1;
    const int quad = lane >> 4, l16 = lane & 15;

    f32x4 acc[4][4];
    for (int i = 0; i < 4; ++i)
        for (int j = 0; j < 4; ++j) acc[i][j] = (f32x4){0.f, 0.f, 0.f, 0.f};

    for (int kb = 0; kb < K / 32; ++kb) {
        __syncthreads();
        // DMA staging: each matrix = 512 slots of 16 B; 2 wave-insts per wave.
        for (int i = 0; i < 2; ++i) {
            int slot = (wave * 2 + i) * 64 + lane;
            int row = slot >> 2, ch = slot & 3;
            int ldsoff = (wave * 2 + i) * 512;  // shorts; +lane*16B by HW
            size_t ga = (size_t)(m0 + row) * K + kb * 32 + ch * 8;
            size_t gb = (size_t)(n0 + row) * K + kb * 32 + ch * 8;
            __builtin_amdgcn_global_load_lds(GLB(Ah + ga), LDS(&As_h[ldsoff]), 16, 0, 0);
            __builtin_amdgcn_global_load_lds(GLB(Bth + gb), LDS(&Bs_h[ldsoff]), 16, 0, 0);
            if constexpr (MODE == 0) {
                __builtin_amdgcn_global_load_lds(GLB(Al + ga), LDS(&As_l[ldsoff]), 16, 0, 0);
                __builtin_amdgcn_global_load_lds(GLB(Btl + gb), LDS(&Bs_l[ldsoff]), 16, 0, 0);
            }
        }
        __syncthreads();

        bf16x8 a[4], b[4];
        for (int mi = 0; mi < 4; ++mi)
            a[mi] = *(const bf16x8*)&As_h[(wr * 64 + mi * 16 + l16) * 32 + quad * 8];
        for (int ni = 0; ni < 4; ++ni)
            b[ni] = *(const bf16x8*)&Bs_h[(wc * 64 + ni * 16 + l16) * 32 + quad * 8];
        for (int mi = 0; mi < 4; ++mi)
            for (int ni = 0; ni < 4; ++ni)
                acc[mi][ni] = MFMA(a[mi], b[ni], acc[mi][ni]);
        if constexpr (MODE == 0) {
            bf16x8 al[4], bl[4];
            for (int mi = 0; mi < 4; ++mi)
                al[mi] = *(const bf16x8*)&As_l[(wr * 64 + mi * 16 + l16) * 32 + quad * 8];
            for (int ni = 0; ni < 4; ++ni)
                bl[ni] = *(const bf16x8*)&Bs_l[(wc * 64 + ni * 16 + l16) * 32 + quad * 8];
            for (int mi = 0; mi < 4; ++mi)
                for (int ni = 0; ni < 4; ++ni) {
                    acc[mi][ni] = MFMA(a[mi], bl[ni], acc[mi][ni]);
                    acc[mi][ni] = MFMA(al[mi], b[ni], acc[mi][ni]);
                }
        }
    }

    // LDS-staged epilogue (C/D layout: col=l16, row=quad*4+r).
    // Q columns pre-scaled by (1/sqrt(128))*log2(e) for exp2-domain softmax.
    const float qscale = 0.12753102455195157f;
    for (int p = 0; p < 2; ++p) {
        __syncthreads();   // also separates K-loop tile reads from Ep writes
        if (wr == p) {
            for (int mi = 0; mi < 4; ++mi) {
                int rl = mi * 16 + quad * 4;
                for (int ni = 0; ni < 4; ++ni) {
                    int cl = wc * 64 + ni * 16 + l16;
                    for (int r = 0; r < 4; ++r) {
                        float v = acc[mi][ni][r];
                        unsigned pk;
                        if constexpr (MODE == 0) {
                            if (blockIdx.y < 8) v *= qscale;
                            short hv = f2bf(v);
                            short lv = f2bf(v - bf2f(hv));
                            pk = (unsigned)(unsigned short)hv |
                                 ((unsigned)(unsigned short)lv << 16);
                        } else {
                            union { float f; unsigned u; } cv; cv.f = v; pk = cv.u;
                        }
                        Ep[(rl + r) * 132 + cl] = pk;
                    }
                }
            }
        }
        __syncthreads();

        if constexpr (MODE == 1) {
            for (int j = 0; j < 8; ++j) {
                int cid = t + j * 256;
                int row = cid >> 5, c = cid & 31;
                f32x4 val;
                for (int q = 0; q < 4; ++q) {
                    union { unsigned u; float f; } cv;
                    cv.u = Ep[row * 132 + c * 4 + q];
                    val[q] = cv.f;
                }
                int gr = m0 + p * 64 + row;
                *(f32x4*)&outf[(size_t)gr * 1024 + n0 + c * 4] = val;
            }
        } else if (blockIdx.y < 9) {
            for (int j = 0; j < 4; ++j) {
                int cid = t + j * 256;
                int row = cid >> 4, c = cid & 15;
                bf16x8 hv, lv;
                for (int q = 0; q < 8; ++q) {
                    unsigned w = Ep[row * 132 + c * 8 + q];
                    hv[q] = (short)(w & 0xffffu);
                    lv[q] = (short)(w >> 16);
                }
                int gr = m0 + p * 64 + row;
                int bb = gr >> 11, s = gr & 2047;
                if (blockIdx.y < 8) {
                    size_t base = (((size_t)(bb * 8 + (n0 >> 7))) * 2048 + s) * 128 + c * 8;
                    *(bf16x8*)&qh[base] = hv;
                    *(bf16x8*)&ql[base] = lv;
                } else {
                    size_t base = ((size_t)bb * 2048 + s) * 128 + c * 8;
                    *(bf16x8*)&kh[base] = hv;
                    *(bf16x8*)&kl[base] = lv;
                }
            }
        } else {
            for (int j = 0; j < 4; ++j) {
                int cid = t + j * 256;
                int d = cid >> 3, sc = cid & 7;
                bf16x8 hv;
                for (int q = 0; q < 8; ++q) {
                    unsigned w = Ep[(sc * 8 + q) * 132 + d];
                    hv[q] = (short)(w & 0xffffu);
                }
                int gr0 = m0 + p * 64 + sc * 8;
                int bb = gr0 >> 11, s0 = gr0 & 2047;
                *(bf16x8*)&vt[((size_t)bb * 128 + d) * 2048 + s0] = hv;
            }
        }
    }
}

// ---------------- flash attention (R11: occupancy 4 blocks/CU) ----------------
// BM=64 (4 waves x 16 q-rows), BN=32 keys/iter; grid (S/64, B*H) = 1024
// blocks -> 4 blocks/CU resident (LDS 29.1 KB, VGPR capped at 128).
// Verified R9 skeleton: K/V staged via global_load_lds (XOR-swizzled
// chunks) between two __syncthreads; setprio around MFMA clusters.
// Defer-max (T13, THR=8 in exp2 domain): skip alpha-rescale when no row's
// tile-max exceeds the running max by >8 (wave-uniform branch).
__global__ __launch_bounds__(256, 4) void attn_k(
    const short* __restrict__ qh, const short* __restrict__ ql,
    const short* __restrict__ kh, const short* __restrict__ kl,
    const short* __restrict__ vt, short* __restrict__ ctx) {
    constexpr int S = 2048, D = 128;
    __shared__ short Kh_s[32 * 128];    // 8 KB (swizzled chunks, no pad)
    __shared__ short Kl_s[32 * 128];    // 8 KB
    __shared__ short Vt_s[128 * 32];    // 8 KB
    __shared__ short P_s[64 * 40];      // 5 KB, per-wave 16-row slices, stride 32+8

    const int bh = blockIdx.y, b = bh >> 3, h = bh & 7;
    const int q0 = blockIdx.x * 64;
    const int t = threadIdx.x, wave = t >> 6, lane = t & 63;
    const int quad = lane >> 4, l16 = lane & 15;
    const int e8 = l16 & 7;             // xor-swizzle key (K: 8-row stripes)
    const int e4 = l16 & 3;             // xor-swizzle key (V: 4-chunk rows)

    // ones B-fragment: B[n=l16][k] = (n==0) ? 1.0bf16 : 0  -> C[., col0] = rowsum
    bf16x8 bones;
    {
        short o = (l16 == 0) ? (short)0x3F80 : (short)0;
        for (int j = 0; j < 8; ++j) bones[j] = o;
    }

    // Q fragments (A-layout A[m=l16][k=quad*8+j]), 1 m-block x 4 k-chunks
    bf16x8 qfh[4], qfl[4];
    {
        size_t qbase = ((size_t)(b * 8 + h) * S + q0 + wave * 16 + l16) * D + quad * 8;
        for (int c = 0; c < 4; ++c) {
            qfh[c] = *(const bf16x8*)(qh + qbase + c * 32);
            qfl[c] = *(const bf16x8*)(ql + qbase + c * 32);
        }
    }

    float mrow[4];
    f32x4 oacc[8], lacc;
    for (int r = 0; r < 4; ++r) mrow[r] = -INFINITY;
    for (int oi = 0; oi < 8; ++oi) oacc[oi] = (f32x4){0.f, 0.f, 0.f, 0.f};
    lacc = (f32x4){0.f, 0.f, 0.f, 0.f};

    for (int kt = 0; kt < S / 32; ++kt) {
        __syncthreads();  // protect LDS reuse
        // --- stage K hi/lo: 32 rows x 128 (16 chunks/row) ---
        {
            int pch = lane & 15;
            for (int i = 0; i < 2; ++i) {
                int rk = wave * 8 + i * 4 + (lane >> 4);
                int j = pch ^ (rk & 7);
                size_t g = ((size_t)b * S + kt * 32 + rk) * D + j * 8;
                int ldsoff = (wave * 8 + i * 4) * 128;
                __builtin_amdgcn_global_load_lds(GLB(kh + g), LDS(&Kh_s[ldsoff]), 16, 0, 0);
                __builtin_amdgcn_global_load_lds(GLB(kl + g), LDS(&Kl_s[ldsoff]), 16, 0, 0);
            }
        }
        // --- stage V^T: 128 rows(o) x 32(s) (4 chunks/row) ---
        {
            int pv = lane & 3;
            for (int i = 0; i < 2; ++i) {
                int rv = wave * 32 + i * 16 + (lane >> 2);
                int j = pv ^ (rv & 3);
                size_t g = ((size_t)b * D + rv) * S + kt * 32 + j * 8;
                int ldsoff = (wave * 32 + i * 16) * 32;
                __builtin_amdgcn_global_load_lds(GLB(vt + g), LDS(&Vt_s[ldsoff]), 16, 0, 0);
            }
        }
        __syncthreads();

        // --- S' = Q' K^T (split: hh + lh + hl); scores already * scale*log2e ---
        f32x4 sacc[2];
        for (int ni = 0; ni < 2; ++ni) sacc[ni] = (f32x4){0.f, 0.f, 0.f, 0.f};
        for (int ni = 0; ni < 2; ++ni) {
            for (int c = 0; c < 4; ++c) {
                int off = (ni * 16 + l16) * 128 + ((c * 4 + quad) ^ e8) * 8;
                bf16x8 kbh = *(const bf16x8*)&Kh_s[off];
                bf16x8 kbl = *(const bf16x8*)&Kl_s[off];
                __builtin_amdgcn_s_setprio(1);
                sacc[ni] = MFMA(qfh[c], kbh, sacc[ni]);
                sacc[ni] = MFMA(qfl[c], kbh, sacc[ni]);
                sacc[ni] = MFMA(qfh[c], kbl, sacc[ni]);
                __builtin_amdgcn_s_setprio(0);
            }
        }

        // --- online softmax (exp2 domain) with defer-max (THR=8) ---
        float rmx[4];
        for (int r = 0; r < 4; ++r) {
            float mx = fmaxf(sacc[0][r], sacc[1][r]);
            for (int off = 8; off; off >>= 1) mx = fmaxf(mx, __shfl_xor(mx, off));
            rmx[r] = mx;
        }
        bool grow = false;
        for (int r = 0; r < 4; ++r) grow |= (rmx[r] > mrow[r] + 8.0f);
        if (__any(grow)) {
            for (int r = 0; r < 4; ++r) {
                float mnew = fmaxf(mrow[r], rmx[r]);
                float alpha = EXP2F(mrow[r] - mnew);
                mrow[r] = mnew;
                lacc[r] *= alpha;
                for (int oi = 0; oi < 8; ++oi) oacc[oi][r] *= alpha;
            }
        }
        for (int ni = 0; ni < 2; ++ni)
            for (int r = 0; r < 4; ++r)
                sacc[ni][r] = EXP2F(sacc[ni][r] - mrow[r]);
        // P -> LDS (C-layout -> A-layout); round-half-up bf16 (2 ops).
        // P_s is per-wave: within-wave RAW through LDS needs no barrier.
        for (int ni = 0; ni < 2; ++ni)
            for (int r = 0; r < 4; ++r) {
                union { float f; unsigned u; } cv; cv.f = sacc[ni][r];
                P_s[(wave * 16 + quad * 4 + r) * 40 + ni * 16 + l16] =
                    (short)((cv.u + 0x8000u) >> 16);
            }

        // --- O += P @ V ; l += P @ ones (MFMA) ---
        {
            bf16x8 pa = *(const bf16x8*)&P_s[(wave * 16 + l16) * 40 + quad * 8];
            lacc = MFMA(pa, bones, lacc);
            for (int oi = 0; oi < 8; ++oi) {
                int off = (oi * 16 + l16) * 32 + (quad ^ e4) * 8;
                bf16x8 vb = *(const bf16x8*)&Vt_s[off];
                __builtin_amdgcn_s_setprio(1);
                oacc[oi] = MFMA(pa, vb, oacc[oi]);
                __builtin_amdgcn_s_setprio(0);
            }
        }
    }

    // epilogue: ctx[b][s][h*128+o] bf16; l lives in col-0 lanes (l16==0)
    for (int r = 0; r < 4; ++r) {
        float ls = __shfl(lacc[r], lane & 48);  // broadcast from l16==0 of quad
        float inv = 1.f / ls;
        int s = q0 + wave * 16 + quad * 4 + r;
        size_t base = ((size_t)b * S + s) * 1024 + h * 128;
        for (int oi = 0; oi < 8; ++oi)
            ctx[base + oi * 16 + l16] = f2bf(oacc[oi][r] * inv);
    }
}

// ---------------- launch ----------------

extern "C" void kernel_launch(void* const* d_in, const int* in_sizes, int n_in,
                              void* d_out, int out_size, void* d_ws, size_t ws_size,
                              hipStream_t stream) {
    const float* x  = (const float*)d_in[0];
    const float* Wq = (const float*)d_in[1];
    const float* Wk = (const float*)d_in[2];
    const float* Wv = (const float*)d_in[3];
    const float* Wo = (const float*)d_in[4];
    float* out = (float*)d_out;

    char* p = (char*)d_ws;
    auto alloc = [&](size_t bytes) { char* r = p; p += bytes; return r; };
    short* xh  = (short*)alloc(16777216);  // x hi    (8192 x 1024)
    short* xl  = (short*)alloc(16777216);  // x lo
    short* wth = (short*)alloc(2621440);   // Wt hi   (1280 x 1024)
    short* wtl = (short*)alloc(2621440);   // Wt lo
    short* wot = (short*)alloc(2097152);   // Wo^T    (1024 x 1024)
    short* qh  = (short*)alloc(16777216);  // Q hi    (B,H,S,D), pre-scaled
    short* ql  = (short*)alloc(16777216);  // Q lo
    short* kh  = (short*)alloc(2097152);   // K hi    (B,S,D)
    short* kl  = (short*)alloc(2097152);   // K lo
    short* vt  = (short*)alloc(2097152);   // V^T     (B,D,S)
    short* ctx = (short*)alloc(16777216);  // ctx     (B,S,H*D)

    split_kernel<<<dim3(2048), dim3(256), 0, stream>>>(x, xh, xl, 8192 * 1024);
    build_wt<<<dim3(1280), dim3(256), 0, stream>>>(Wq, Wk, Wv, wth, wtl);
    build_wot<<<dim3(1024), dim3(256), 0, stream>>>(Wo, wot);
    gemm_k<0><<<dim3(64, 10), dim3(256), 0, stream>>>(xh, xl, wth, wtl,
                                                      qh, ql, kh, kl, vt, nullptr);
    attn_k<<<dim3(32, 32), dim3(256), 0, stream>>>(qh, ql, kh, kl, vt, ctx);
    gemm_k<1><<<dim3(64, 8), dim3(256), 0, stream>>>(ctx, nullptr, wot, nullptr,
                                                     nullptr, nullptr, nullptr, nullptr,
                                                     nullptr, out);
}

// Round 6
// 366.581 us; speedup vs baseline: 1.1248x; 1.1248x over previous
//
#include <hip/hip_runtime.h>
#include <math.h>

// ---------------------------------------------------------------------------
// Attention: B=4, S=2048, E=1024, H=8, O=128 (fp32 in/out)
// Split-bf16 (hi+lo) MFMA for x->QK and QK^T (precision-critical), plain bf16
// for V / PV / ctx@Wo. Flash-attention (no S x S materialize).
// R1-R5: see history. R6: 2-barrier attn (369.8us total).
// R7/R8: barrier-free attn REGRESSED (latency-bound at 2 waves/SIMD).
// R9: R6 + setprio: attn 168.7us (Mfma 36/VALU 31/Occ 20.6). BEST attn.
// R10: dbuf+raw-barrier NEUTRAL (172.5us) -> stall is not load latency.
// R11: BM=64/BN=32 4-blocks/CU REGRESSED (228us): Occ 42 but Mfma 27.5 --
//     halving BN halved per-tile MFMA density while doubling per-tile fixed
//     costs; V-tile 64B-stride tripled bank conflicts (9.4M->26M).
//     Occupancy is NOT the binding constraint; per-tile density + the
//     serial QK->softmax->PV chain is.
// R12 (this round): revert attn to R9 structure exactly; ONE additive:
//     defer-max (T13, THR=8): wave-uniform skip of the alpha-rescale
//     (256 v_mul + exp2s per iter) when no row's tile-max grows >8.
//     Next candidates if <3%: swapped-QK in-register softmax; gemm0.
// ---------------------------------------------------------------------------

typedef __attribute__((ext_vector_type(8))) short bf16x8;   // 8 bf16 (4 VGPRs)
typedef __attribute__((ext_vector_type(4))) float f32x4;

#define MFMA(a, b, c) __builtin_amdgcn_mfma_f32_16x16x32_bf16((a), (b), (c), 0, 0, 0)
#define GLB(p) ((const __attribute__((address_space(1))) void*)(p))
#define LDS(p) ((__attribute__((address_space(3))) void*)(p))

#if __has_builtin(__builtin_amdgcn_exp2f)
#define EXP2F(x) __builtin_amdgcn_exp2f(x)
#else
#define EXP2F(x) exp2f(x)
#endif

__device__ __forceinline__ short f2bf(float f) {
    union { float f; unsigned u; } v; v.f = f;
    unsigned r = v.u + 0x7fffu + ((v.u >> 16) & 1u);   // RNE
    return (short)(r >> 16);
}
__device__ __forceinline__ float bf2f(short s) {
    union { unsigned u; float f; } v; v.u = ((unsigned)(unsigned short)s) << 16;
    return v.f;
}

// ---------------- prep kernels ----------------

__global__ __launch_bounds__(256) void split_kernel(
    const float* __restrict__ x, short* __restrict__ hi, short* __restrict__ lo, int n) {
    for (int i = blockIdx.x * blockDim.x + threadIdx.x; i < n; i += gridDim.x * blockDim.x) {
        float f = x[i];
        short h = f2bf(f);
        hi[i] = h;
        lo[i] = f2bf(f - bf2f(h));
    }
}

__global__ __launch_bounds__(256) void build_wt(
    const float* __restrict__ Wq, const float* __restrict__ Wk, const float* __restrict__ Wv,
    short* __restrict__ wth, short* __restrict__ wtl) {
    const int total = 1280 * 1024;
    for (int idx = blockIdx.x * blockDim.x + threadIdx.x; idx < total; idx += gridDim.x * blockDim.x) {
        int n = idx >> 10, k = idx & 1023;
        float f;
        if (n < 1024)      f = Wq[((size_t)(n >> 7) * 1024 + k) * 128 + (n & 127)];
        else if (n < 1152) f = Wk[(size_t)k * 128 + (n - 1024)];
        else               f = Wv[(size_t)k * 128 + (n - 1152)];
        short h = f2bf(f);
        wth[idx] = h;
        wtl[idx] = f2bf(f - bf2f(h));
    }
}

__global__ __launch_bounds__(256) void build_wot(
    const float* __restrict__ Wo, short* __restrict__ wot) {
    const int total = 1024 * 1024;
    for (int idx = blockIdx.x * blockDim.x + threadIdx.x; idx < total; idx += gridDim.x * blockDim.x) {
        int e = idx >> 10, k = idx & 1023;
        wot[idx] = f2bf(Wo[(size_t)k * 1024 + e]);
    }
}

// ---------------- GEMM: C(M x N) = A(M x 1024) @ Bt(N x 1024)^T ----------------
// K-tiles and epilogue staging share one LDS allocation (disjoint lifetimes,
// barrier-separated): 33.8 KB -> 4 blocks/CU.
template <int MODE>
__global__ __launch_bounds__(256, 4) void gemm_k(
    const short* __restrict__ Ah, const short* __restrict__ Al,
    const short* __restrict__ Bth, const short* __restrict__ Btl,
    short* __restrict__ qh, short* __restrict__ ql,
    short* __restrict__ kh, short* __restrict__ kl,
    short* __restrict__ vt, float* __restrict__ outf) {
    constexpr int K = 1024;
    __shared__ __align__(16) char smem[33792];
    short* As_h = (short*)smem;                 // 128x32 = 8192 B
    short* Bs_h = (short*)(smem + 8192);
    short* As_l = (short*)(smem + 16384);       // MODE 0 only
    short* Bs_l = (short*)(smem + 24576);
    unsigned* Ep = (unsigned*)smem;             // 64x132 u32 = 33792 B (epilogue)

    const int t = threadIdx.x;
    const int m0 = blockIdx.x * 128, n0 = blockIdx.y * 128;
    const int wave = t >> 6, lane = t & 63;
    const int wr = wave >> 1, wc = wave & 1;
    const int quad = lane >> 4, l16 = lane & 15;

    f32x4 acc[4][4];
    for (int i = 0; i < 4; ++i)
        for (int j = 0; j < 4; ++j) acc[i][j] = (f32x4){0.f, 0.f, 0.f, 0.f};

    for (int kb = 0; kb < K / 32; ++kb) {
        __syncthreads();
        // DMA staging: each matrix = 512 slots of 16 B; 2 wave-insts per wave.
        for (int i = 0; i < 2; ++i) {
            int slot = (wave * 2 + i) * 64 + lane;
            int row = slot >> 2, ch = slot & 3;
            int ldsoff = (wave * 2 + i) * 512;  // shorts; +lane*16B by HW
            size_t ga = (size_t)(m0 + row) * K + kb * 32 + ch * 8;
            size_t gb = (size_t)(n0 + row) * K + kb * 32 + ch * 8;
            __builtin_amdgcn_global_load_lds(GLB(Ah + ga), LDS(&As_h[ldsoff]), 16, 0, 0);
            __builtin_amdgcn_global_load_lds(GLB(Bth + gb), LDS(&Bs_h[ldsoff]), 16, 0, 0);
            if constexpr (MODE == 0) {
                __builtin_amdgcn_global_load_lds(GLB(Al + ga), LDS(&As_l[ldsoff]), 16, 0, 0);
                __builtin_amdgcn_global_load_lds(GLB(Btl + gb), LDS(&Bs_l[ldsoff]), 16, 0, 0);
            }
        }
        __syncthreads();

        bf16x8 a[4], b[4];
        for (int mi = 0; mi < 4; ++mi)
            a[mi] = *(const bf16x8*)&As_h[(wr * 64 + mi * 16 + l16) * 32 + quad * 8];
        for (int ni = 0; ni < 4; ++ni)
            b[ni] = *(const bf16x8*)&Bs_h[(wc * 64 + ni * 16 + l16) * 32 + quad * 8];
        for (int mi = 0; mi < 4; ++mi)
            for (int ni = 0; ni < 4; ++ni)
                acc[mi][ni] = MFMA(a[mi], b[ni], acc[mi][ni]);
        if constexpr (MODE == 0) {
            bf16x8 al[4], bl[4];
            for (int mi = 0; mi < 4; ++mi)
                al[mi] = *(const bf16x8*)&As_l[(wr * 64 + mi * 16 + l16) * 32 + quad * 8];
            for (int ni = 0; ni < 4; ++ni)
                bl[ni] = *(const bf16x8*)&Bs_l[(wc * 64 + ni * 16 + l16) * 32 + quad * 8];
            for (int mi = 0; mi < 4; ++mi)
                for (int ni = 0; ni < 4; ++ni) {
                    acc[mi][ni] = MFMA(a[mi], bl[ni], acc[mi][ni]);
                    acc[mi][ni] = MFMA(al[mi], b[ni], acc[mi][ni]);
                }
        }
    }

    // LDS-staged epilogue (C/D layout: col=l16, row=quad*4+r).
    // Q columns pre-scaled by (1/sqrt(128))*log2(e) for exp2-domain softmax.
    const float qscale = 0.12753102455195157f;
    for (int p = 0; p < 2; ++p) {
        __syncthreads();   // also separates K-loop tile reads from Ep writes
        if (wr == p) {
            for (int mi = 0; mi < 4; ++mi) {
                int rl = mi * 16 + quad * 4;
                for (int ni = 0; ni < 4; ++ni) {
                    int cl = wc * 64 + ni * 16 + l16;
                    for (int r = 0; r < 4; ++r) {
                        float v = acc[mi][ni][r];
                        unsigned pk;
                        if constexpr (MODE == 0) {
                            if (blockIdx.y < 8) v *= qscale;
                            short hv = f2bf(v);
                            short lv = f2bf(v - bf2f(hv));
                            pk = (unsigned)(unsigned short)hv |
                                 ((unsigned)(unsigned short)lv << 16);
                        } else {
                            union { float f; unsigned u; } cv; cv.f = v; pk = cv.u;
                        }
                        Ep[(rl + r) * 132 + cl] = pk;
                    }
                }
            }
        }
        __syncthreads();

        if constexpr (MODE == 1) {
            for (int j = 0; j < 8; ++j) {
                int cid = t + j * 256;
                int row = cid >> 5, c = cid & 31;
                f32x4 val;
                for (int q = 0; q < 4; ++q) {
                    union { unsigned u; float f; } cv;
                    cv.u = Ep[row * 132 + c * 4 + q];
                    val[q] = cv.f;
                }
                int gr = m0 + p * 64 + row;
                *(f32x4*)&outf[(size_t)gr * 1024 + n0 + c * 4] = val;
            }
        } else if (blockIdx.y < 9) {
            for (int j = 0; j < 4; ++j) {
                int cid = t + j * 256;
                int row = cid >> 4, c = cid & 15;
                bf16x8 hv, lv;
                for (int q = 0; q < 8; ++q) {
                    unsigned w = Ep[row * 132 + c * 8 + q];
                    hv[q] = (short)(w & 0xffffu);
                    lv[q] = (short)(w >> 16);
                }
                int gr = m0 + p * 64 + row;
                int bb = gr >> 11, s = gr & 2047;
                if (blockIdx.y < 8) {
                    size_t base = (((size_t)(bb * 8 + (n0 >> 7))) * 2048 + s) * 128 + c * 8;
                    *(bf16x8*)&qh[base] = hv;
                    *(bf16x8*)&ql[base] = lv;
                } else {
                    size_t base = ((size_t)bb * 2048 + s) * 128 + c * 8;
                    *(bf16x8*)&kh[base] = hv;
                    *(bf16x8*)&kl[base] = lv;
                }
            }
        } else {
            for (int j = 0; j < 4; ++j) {
                int cid = t + j * 256;
                int d = cid >> 3, sc = cid & 7;
                bf16x8 hv;
                for (int q = 0; q < 8; ++q) {
                    unsigned w = Ep[(sc * 8 + q) * 132 + d];
                    hv[q] = (short)(w & 0xffffu);
                }
                int gr0 = m0 + p * 64 + sc * 8;
                int bb = gr0 >> 11, s0 = gr0 & 2047;
                *(bf16x8*)&vt[((size_t)bb * 128 + d) * 2048 + s0] = hv;
            }
        }
    }
}

// ---------------- flash attention (R9 structure + defer-max) ----------------
// grid (S/128, B*H); 4 waves x 32 query rows (2 m-blocks); BN=64 keys/iter.
// K/V staged via global_load_lds with XOR-swizzled chunks between the two
// barriers (single drain point; wave-level overlap hides the rest).
// setprio(1) around MFMA clusters (kept from R9).
// R12: defer-max (T13, THR=8 exp2-domain): skip alpha-rescale + max update
// unless some row's tile-max exceeds running max by >8 (wave-uniform).
__global__ __launch_bounds__(256, 2) void attn_k(
    const short* __restrict__ qh, const short* __restrict__ ql,
    const short* __restrict__ kh, const short* __restrict__ kl,
    const short* __restrict__ vt, short* __restrict__ ctx) {
    constexpr int S = 2048, D = 128;
    __shared__ short Kh_s[64 * 128];    // swizzled, no pad
    __shared__ short Kl_s[64 * 128];
    __shared__ short Vt_s[128 * 64];    // swizzled, no pad
    __shared__ short P_s[128 * 72];     // per-wave 32-row slices, stride 64+8

    const int bh = blockIdx.y, b = bh >> 3, h = bh & 7;
    const int q0 = blockIdx.x * 128;
    const int t = threadIdx.x, wave = t >> 6, lane = t & 63;
    const int quad = lane >> 4, l16 = lane & 15;
    const int e8 = l16 & 7;             // xor-swizzle key

    // ones B-fragment: B[n=l16][k] = (n==0) ? 1.0bf16 : 0  -> C[., col0] = rowsum
    bf16x8 bones;
    {
        short o = (l16 == 0) ? (short)0x3F80 : (short)0;
        for (int j = 0; j < 8; ++j) bones[j] = o;
    }

    // Q fragments (A-layout A[m=l16][k=quad*8+j]), 2 m-blocks x 4 k-chunks
    bf16x8 qfh[2][4], qfl[2][4];
    for (int mb = 0; mb < 2; ++mb) {
        size_t qbase = ((size_t)(b * 8 + h) * S + q0 + wave * 32 + mb * 16 + l16) * D + quad * 8;
        for (int c = 0; c < 4; ++c) {
            qfh[mb][c] = *(const bf16x8*)(qh + qbase + c * 32);
            qfl[mb][c] = *(const bf16x8*)(ql + qbase + c * 32);
        }
    }

    float mrow[2][4];
    f32x4 oacc[2][8], lacc[2];
    for (int mb = 0; mb < 2; ++mb) {
        for (int r = 0; r < 4; ++r) mrow[mb][r] = -INFINITY;
        for (int oi = 0; oi < 8; ++oi) oacc[mb][oi] = (f32x4){0.f, 0.f, 0.f, 0.f};
        lacc[mb] = (f32x4){0.f, 0.f, 0.f, 0.f};
    }

    for (int kt = 0; kt < S / 64; ++kt) {
        __syncthreads();  // protect LDS reuse
        // --- stage K hi/lo: 64 rows x 128 ---
        {
            int pch = lane & 15;
            for (int i = 0; i < 4; ++i) {
                int rk = wave * 16 + i * 4 + (lane >> 4);
                int j = pch ^ (rk & 7);
                size_t g = ((size_t)b * S + kt * 64 + rk) * D + j * 8;
                int ldsoff = (wave * 16 + i * 4) * 128;
                __builtin_amdgcn_global_load_lds(GLB(kh + g), LDS(&Kh_s[ldsoff]), 16, 0, 0);
                __builtin_amdgcn_global_load_lds(GLB(kl + g), LDS(&Kl_s[ldsoff]), 16, 0, 0);
            }
        }
        // --- stage V^T: 128 rows(o) x 64(s) ---
        {
            int pch = lane & 7;
            for (int i = 0; i < 4; ++i) {
                int rv = wave * 32 + i * 8 + (lane >> 3);
                int j = pch ^ (rv & 7);
                size_t g = ((size_t)b * D + rv) * S + kt * 64 + j * 8;
                int ldsoff = (wave * 32 + i * 8) * 64;
                __builtin_amdgcn_global_load_lds(GLB(vt + g), LDS(&Vt_s[ldsoff]), 16, 0, 0);
            }
        }
        __syncthreads();

        // --- S' = Q' K^T (split: hh + lh + hl); scores already * scale*log2e ---
        f32x4 sacc[2][4];
        for (int mb = 0; mb < 2; ++mb)
            for (int ni = 0; ni < 4; ++ni) sacc[mb][ni] = (f32x4){0.f, 0.f, 0.f, 0.f};
        for (int ni = 0; ni < 4; ++ni) {
            for (int c = 0; c < 4; ++c) {
                int off = (ni * 16 + l16) * 128 + ((c * 4 + quad) ^ e8) * 8;
                bf16x8 kbh = *(const bf16x8*)&Kh_s[off];
                bf16x8 kbl = *(const bf16x8*)&Kl_s[off];
                __builtin_amdgcn_s_setprio(1);
                for (int mb = 0; mb < 2; ++mb) {
                    sacc[mb][ni] = MFMA(qfh[mb][c], kbh, sacc[mb][ni]);
                    sacc[mb][ni] = MFMA(qfl[mb][c], kbh, sacc[mb][ni]);
                    sacc[mb][ni] = MFMA(qfh[mb][c], kbl, sacc[mb][ni]);
                }
                __builtin_amdgcn_s_setprio(0);
            }
        }

        // --- online softmax (exp2 domain) with defer-max (THR=8) ---
        float rmx[2][4];
        for (int mb = 0; mb < 2; ++mb)
            for (int r = 0; r < 4; ++r) {
                float mx = fmaxf(fmaxf(sacc[mb][0][r], sacc[mb][1][r]),
                                 fmaxf(sacc[mb][2][r], sacc[mb][3][r]));
                for (int off = 8; off; off >>= 1) mx = fmaxf(mx, __shfl_xor(mx, off));
                rmx[mb][r] = mx;
            }
        bool grow = false;
        for (int mb = 0; mb < 2; ++mb)
            for (int r = 0; r < 4; ++r) grow |= (rmx[mb][r] > mrow[mb][r] + 8.0f);
        if (__any(grow)) {
            for (int mb = 0; mb < 2; ++mb)
                for (int r = 0; r < 4; ++r) {
                    float mnew = fmaxf(mrow[mb][r], rmx[mb][r]);
                    float alpha = EXP2F(mrow[mb][r] - mnew);
                    mrow[mb][r] = mnew;
                    lacc[mb][r] *= alpha;
                    for (int oi = 0; oi < 8; ++oi) oacc[mb][oi][r] *= alpha;
                }
        }
        for (int mb = 0; mb < 2; ++mb) {
            for (int ni = 0; ni < 4; ++ni)
                for (int r = 0; r < 4; ++r)
                    sacc[mb][ni][r] = EXP2F(sacc[mb][ni][r] - mrow[mb][r]);
            // P -> LDS (C-layout -> A-layout); round-half-up bf16 (2 ops).
            // P bounded by 2^8 under defer-max; bf16 range fine.
            for (int ni = 0; ni < 4; ++ni)
                for (int r = 0; r < 4; ++r) {
                    union { float f; unsigned u; } cv; cv.f = sacc[mb][ni][r];
                    P_s[(wave * 32 + mb * 16 + quad * 4 + r) * 72 + ni * 16 + l16] =
                        (short)((cv.u + 0x8000u) >> 16);
                }
        }

        // --- O += P @ V ; l += P @ ones (MFMA) ---
        for (int c2 = 0; c2 < 2; ++c2) {
            bf16x8 pa[2];
            for (int mb = 0; mb < 2; ++mb) {
                pa[mb] = *(const bf16x8*)&P_s[(wave * 32 + mb * 16 + l16) * 72 + c2 * 32 + quad * 8];
                lacc[mb] = MFMA(pa[mb], bones, lacc[mb]);
            }
            for (int oi = 0; oi < 8; ++oi) {
                int off = (oi * 16 + l16) * 64 + ((c2 * 4 + quad) ^ e8) * 8;
                bf16x8 vb = *(const bf16x8*)&Vt_s[off];
                __builtin_amdgcn_s_setprio(1);
                for (int mb = 0; mb < 2; ++mb)
                    oacc[mb][oi] = MFMA(pa[mb], vb, oacc[mb][oi]);
                __builtin_amdgcn_s_setprio(0);
            }
        }
    }

    // epilogue: ctx[b][s][h*128+o] bf16; l lives in col-0 lanes (l16==0)
    for (int mb = 0; mb < 2; ++mb) {
        for (int r = 0; r < 4; ++r) {
            float ls = __shfl(lacc[mb][r], lane & 48);  // broadcast from l16==0 of quad
            float inv = 1.f / ls;
            int s = q0 + wave * 32 + mb * 16 + quad * 4 + r;
            size_t base = ((size_t)b * S + s) * 1024 + h * 128;
            for (int oi = 0; oi < 8; ++oi)
                ctx[base + oi * 16 + l16] = f2bf(oacc[mb][oi][r] * inv);
        }
    }
}

// ---------------- launch ----------------

extern "C" void kernel_launch(void* const* d_in, const int* in_sizes, int n_in,
                              void* d_out, int out_size, void* d_ws, size_t ws_size,
                              hipStream_t stream) {
    const float* x  = (const float*)d_in[0];
    const float* Wq = (const float*)d_in[1];
    const float* Wk = (const float*)d_in[2];
    const float* Wv = (const float*)d_in[3];
    const float* Wo = (const float*)d_in[4];
    float* out = (float*)d_out;

    char* p = (char*)d_ws;
    auto alloc = [&](size_t bytes) { char* r = p; p += bytes; return r; };
    short* xh  = (short*)alloc(16777216);  // x hi    (8192 x 1024)
    short* xl  = (short*)alloc(16777216);  // x lo
    short* wth = (short*)alloc(2621440);   // Wt hi   (1280 x 1024)
    short* wtl = (short*)alloc(2621440);   // Wt lo
    short* wot = (short*)alloc(2097152);   // Wo^T    (1024 x 1024)
    short* qh  = (short*)alloc(16777216);  // Q hi    (B,H,S,D), pre-scaled
    short* ql  = (short*)alloc(16777216);  // Q lo
    short* kh  = (short*)alloc(2097152);   // K hi    (B,S,D)
    short* kl  = (short*)alloc(2097152);   // K lo
    short* vt  = (short*)alloc(2097152);   // V^T     (B,D,S)
    short* ctx = (short*)alloc(16777216);  // ctx     (B,S,H*D)

    split_kernel<<<dim3(2048), dim3(256), 0, stream>>>(x, xh, xl, 8192 * 1024);
    build_wt<<<dim3(1280), dim3(256), 0, stream>>>(Wq, Wk, Wv, wth, wtl);
    build_wot<<<dim3(1024), dim3(256), 0, stream>>>(Wo, wot);
    gemm_k<0><<<dim3(64, 10), dim3(256), 0, stream>>>(xh, xl, wth, wtl,
                                                      qh, ql, kh, kl, vt, nullptr);
    attn_k<<<dim3(16, 32), dim3(256), 0, stream>>>(qh, ql, kh, kl, vt, ctx);
    gemm_k<1><<<dim3(64, 8), dim3(256), 0, stream>>>(ctx, nullptr, wot, nullptr,
                                                     nullptr, nullptr, nullptr, nullptr,
                                                     nullptr, out);
}

// Round 8
// 358.957 us; speedup vs baseline: 1.1487x; 1.0212x over previous
//
#include <hip/hip_runtime.h>
#include <math.h>

// ---------------------------------------------------------------------------
// Attention: B=4, S=2048, E=1024, H=8, O=128 (fp32 in/out)
// Split-bf16 (hi+lo) MFMA for x->QK and QK^T (precision-critical), plain bf16
// for V / PV / ctx@Wo. Flash-attention (no S x S materialize).
// R1-R5: see history. R6: 2-barrier attn (369.8us total).
// R7/R8: barrier-free attn REGRESSED (latency-bound at 2 waves/SIMD).
// R9: R6 + setprio: attn 168.7us (Mfma 36/VALU 31/Occ 20.6). BEST attn.
// R10: dbuf+raw-barrier NEUTRAL (172.5us) -> stall is not load latency.
// R11: BM=64/BN=32 4-blocks/CU REGRESSED (228us): occupancy not binding.
// R12: defer-max NEUTRAL (170.6us) -> softmax alpha-rescale not critical;
//     reverted. Invariant across R9/R10/R12: per-SIMD 2 waves x (2560 MFMA
//     + 1950 VALU) ~ 9000 cyc vs 12.7k wall -> PHASE LOCKSTEP: co-resident
//     waves sit in the same phase, pipes alternate idling.
// R13: (1) attn FORCED ANTI-PHASE: co-resident partner blocks (linear id
//     >= 256) take a one-time ~5.8k-cyc s_sleep before the loop -> block
//     A's MFMA overlaps block B's softmax on every SIMD. Cheap, diagnostic.
//     (2) gemm0: V column-block (y==9) skips lo staging + lo MFMAs.
// R14: identical re-submit of R13 (broker timeout; R13 never measured).
// ---------------------------------------------------------------------------

typedef __attribute__((ext_vector_type(8))) short bf16x8;   // 8 bf16 (4 VGPRs)
typedef __attribute__((ext_vector_type(4))) float f32x4;

#define MFMA(a, b, c) __builtin_amdgcn_mfma_f32_16x16x32_bf16((a), (b), (c), 0, 0, 0)
#define GLB(p) ((const __attribute__((address_space(1))) void*)(p))
#define LDS(p) ((__attribute__((address_space(3))) void*)(p))

#if __has_builtin(__builtin_amdgcn_exp2f)
#define EXP2F(x) __builtin_amdgcn_exp2f(x)
#else
#define EXP2F(x) exp2f(x)
#endif

__device__ __forceinline__ short f2bf(float f) {
    union { float f; unsigned u; } v; v.f = f;
    unsigned r = v.u + 0x7fffu + ((v.u >> 16) & 1u);   // RNE
    return (short)(r >> 16);
}
__device__ __forceinline__ float bf2f(short s) {
    union { unsigned u; float f; } v; v.u = ((unsigned)(unsigned short)s) << 16;
    return v.f;
}

// ---------------- prep kernels ----------------

__global__ __launch_bounds__(256) void split_kernel(
    const float* __restrict__ x, short* __restrict__ hi, short* __restrict__ lo, int n) {
    for (int i = blockIdx.x * blockDim.x + threadIdx.x; i < n; i += gridDim.x * blockDim.x) {
        float f = x[i];
        short h = f2bf(f);
        hi[i] = h;
        lo[i] = f2bf(f - bf2f(h));
    }
}

__global__ __launch_bounds__(256) void build_wt(
    const float* __restrict__ Wq, const float* __restrict__ Wk, const float* __restrict__ Wv,
    short* __restrict__ wth, short* __restrict__ wtl) {
    const int total = 1280 * 1024;
    for (int idx = blockIdx.x * blockDim.x + threadIdx.x; idx < total; idx += gridDim.x * blockDim.x) {
        int n = idx >> 10, k = idx & 1023;
        float f;
        if (n < 1024)      f = Wq[((size_t)(n >> 7) * 1024 + k) * 128 + (n & 127)];
        else if (n < 1152) f = Wk[(size_t)k * 128 + (n - 1024)];
        else               f = Wv[(size_t)k * 128 + (n - 1152)];
        short h = f2bf(f);
        wth[idx] = h;
        wtl[idx] = f2bf(f - bf2f(h));
    }
}

__global__ __launch_bounds__(256) void build_wot(
    const float* __restrict__ Wo, short* __restrict__ wot) {
    const int total = 1024 * 1024;
    for (int idx = blockIdx.x * blockDim.x + threadIdx.x; idx < total; idx += gridDim.x * blockDim.x) {
        int e = idx >> 10, k = idx & 1023;
        wot[idx] = f2bf(Wo[(size_t)k * 1024 + e]);
    }
}

// ---------------- GEMM: C(M x N) = A(M x 1024) @ Bt(N x 1024)^T ----------------
// K-tiles and epilogue staging share one LDS allocation (disjoint lifetimes,
// barrier-separated): 33.8 KB -> 4 blocks/CU.
// R13: y==9 (V block) only consumes the hi result -> skip lo staging + lo
// MFMAs there (block-uniform branch; barriers unaffected).
template <int MODE>
__global__ __launch_bounds__(256, 4) void gemm_k(
    const short* __restrict__ Ah, const short* __restrict__ Al,
    const short* __restrict__ Bth, const short* __restrict__ Btl,
    short* __restrict__ qh, short* __restrict__ ql,
    short* __restrict__ kh, short* __restrict__ kl,
    short* __restrict__ vt, float* __restrict__ outf) {
    constexpr int K = 1024;
    __shared__ __align__(16) char smem[33792];
    short* As_h = (short*)smem;                 // 128x32 = 8192 B
    short* Bs_h = (short*)(smem + 8192);
    short* As_l = (short*)(smem + 16384);       // MODE 0 only
    short* Bs_l = (short*)(smem + 24576);
    unsigned* Ep = (unsigned*)smem;             // 64x132 u32 = 33792 B (epilogue)

    const int t = threadIdx.x;
    const int m0 = blockIdx.x * 128, n0 = blockIdx.y * 128;
    const int wave = t >> 6, lane = t & 63;
    const int wr = wave >> 1, wc = wave & 1;
    const int quad = lane >> 4, l16 = lane & 15;
    const bool needLo = (MODE == 0) && (blockIdx.y < 9);   // V block skips lo

    f32x4 acc[4][4];
    for (int i = 0; i < 4; ++i)
        for (int j = 0; j < 4; ++j) acc[i][j] = (f32x4){0.f, 0.f, 0.f, 0.f};

    for (int kb = 0; kb < K / 32; ++kb) {
        __syncthreads();
        // DMA staging: each matrix = 512 slots of 16 B; 2 wave-insts per wave.
        for (int i = 0; i < 2; ++i) {
            int slot = (wave * 2 + i) * 64 + lane;
            int row = slot >> 2, ch = slot & 3;
            int ldsoff = (wave * 2 + i) * 512;  // shorts; +lane*16B by HW
            size_t ga = (size_t)(m0 + row) * K + kb * 32 + ch * 8;
            size_t gb = (size_t)(n0 + row) * K + kb * 32 + ch * 8;
            __builtin_amdgcn_global_load_lds(GLB(Ah + ga), LDS(&As_h[ldsoff]), 16, 0, 0);
            __builtin_amdgcn_global_load_lds(GLB(Bth + gb), LDS(&Bs_h[ldsoff]), 16, 0, 0);
            if constexpr (MODE == 0) {
                if (needLo) {
                    __builtin_amdgcn_global_load_lds(GLB(Al + ga), LDS(&As_l[ldsoff]), 16, 0, 0);
                    __builtin_amdgcn_global_load_lds(GLB(Btl + gb), LDS(&Bs_l[ldsoff]), 16, 0, 0);
                }
            }
        }
        __syncthreads();

        bf16x8 a[4], b[4];
        for (int mi = 0; mi < 4; ++mi)
            a[mi] = *(const bf16x8*)&As_h[(wr * 64 + mi * 16 + l16) * 32 + quad * 8];
        for (int ni = 0; ni < 4; ++ni)
            b[ni] = *(const bf16x8*)&Bs_h[(wc * 64 + ni * 16 + l16) * 32 + quad * 8];
        for (int mi = 0; mi < 4; ++mi)
            for (int ni = 0; ni < 4; ++ni)
                acc[mi][ni] = MFMA(a[mi], b[ni], acc[mi][ni]);
        if constexpr (MODE == 0) {
            if (needLo) {
                bf16x8 al[4], bl[4];
                for (int mi = 0; mi < 4; ++mi)
                    al[mi] = *(const bf16x8*)&As_l[(wr * 64 + mi * 16 + l16) * 32 + quad * 8];
                for (int ni = 0; ni < 4; ++ni)
                    bl[ni] = *(const bf16x8*)&Bs_l[(wc * 64 + ni * 16 + l16) * 32 + quad * 8];
                for (int mi = 0; mi < 4; ++mi)
                    for (int ni = 0; ni < 4; ++ni) {
                        acc[mi][ni] = MFMA(a[mi], bl[ni], acc[mi][ni]);
                        acc[mi][ni] = MFMA(al[mi], b[ni], acc[mi][ni]);
                    }
            }
        }
    }

    // LDS-staged epilogue (C/D layout: col=l16, row=quad*4+r).
    // Q columns pre-scaled by (1/sqrt(128))*log2(e) for exp2-domain softmax.
    const float qscale = 0.12753102455195157f;
    for (int p = 0; p < 2; ++p) {
        __syncthreads();   // also separates K-loop tile reads from Ep writes
        if (wr == p) {
            for (int mi = 0; mi < 4; ++mi) {
                int rl = mi * 16 + quad * 4;
                for (int ni = 0; ni < 4; ++ni) {
                    int cl = wc * 64 + ni * 16 + l16;
                    for (int r = 0; r < 4; ++r) {
                        float v = acc[mi][ni][r];
                        unsigned pk;
                        if constexpr (MODE == 0) {
                            if (blockIdx.y < 8) v *= qscale;
                            short hv = f2bf(v);
                            short lv = f2bf(v - bf2f(hv));
                            pk = (unsigned)(unsigned short)hv |
                                 ((unsigned)(unsigned short)lv << 16);
                        } else {
                            union { float f; unsigned u; } cv; cv.f = v; pk = cv.u;
                        }
                        Ep[(rl + r) * 132 + cl] = pk;
                    }
                }
            }
        }
        __syncthreads();

        if constexpr (MODE == 1) {
            for (int j = 0; j < 8; ++j) {
                int cid = t + j * 256;
                int row = cid >> 5, c = cid & 31;
                f32x4 val;
                for (int q = 0; q < 4; ++q) {
                    union { unsigned u; float f; } cv;
                    cv.u = Ep[row * 132 + c * 4 + q];
                    val[q] = cv.f;
                }
                int gr = m0 + p * 64 + row;
                *(f32x4*)&outf[(size_t)gr * 1024 + n0 + c * 4] = val;
            }
        } else if (blockIdx.y < 9) {
            for (int j = 0; j < 4; ++j) {
                int cid = t + j * 256;
                int row = cid >> 4, c = cid & 15;
                bf16x8 hv, lv;
                for (int q = 0; q < 8; ++q) {
                    unsigned w = Ep[row * 132 + c * 8 + q];
                    hv[q] = (short)(w & 0xffffu);
                    lv[q] = (short)(w >> 16);
                }
                int gr = m0 + p * 64 + row;
                int bb = gr >> 11, s = gr & 2047;
                if (blockIdx.y < 8) {
                    size_t base = (((size_t)(bb * 8 + (n0 >> 7))) * 2048 + s) * 128 + c * 8;
                    *(bf16x8*)&qh[base] = hv;
                    *(bf16x8*)&ql[base] = lv;
                } else {
                    size_t base = ((size_t)bb * 2048 + s) * 128 + c * 8;
                    *(bf16x8*)&kh[base] = hv;
                    *(bf16x8*)&kl[base] = lv;
                }
            }
        } else {
            for (int j = 0; j < 4; ++j) {
                int cid = t + j * 256;
                int d = cid >> 3, sc = cid & 7;
                bf16x8 hv;
                for (int q = 0; q < 8; ++q) {
                    unsigned w = Ep[(sc * 8 + q) * 132 + d];
                    hv[q] = (short)(w & 0xffffu);
                }
                int gr0 = m0 + p * 64 + sc * 8;
                int bb = gr0 >> 11, s0 = gr0 & 2047;
                *(bf16x8*)&vt[((size_t)bb * 128 + d) * 2048 + s0] = hv;
            }
        }
    }
}

// ---------------- flash attention (R9 structure + anti-phase) ----------------
// grid (S/128, B*H); 4 waves x 32 query rows (2 m-blocks); BN=64 keys/iter.
// K/V staged via global_load_lds with XOR-swizzled chunks between the two
// barriers (single drain point; wave-level overlap hides the rest).
// setprio(1) around MFMA clusters (kept from R9).
// R13: co-resident partner blocks (linear id >= 256, second dispatch round
// on each CU) take a one-time ~5.8k-cycle s_sleep before the main loop ->
// the two blocks on a CU run anti-phased: one block's MFMA phase overlaps
// the other's softmax VALU phase on every SIMD.
__global__ __launch_bounds__(256, 2) void attn_k(
    const short* __restrict__ qh, const short* __restrict__ ql,
    const short* __restrict__ kh, const short* __restrict__ kl,
    const short* __restrict__ vt, short* __restrict__ ctx) {
    constexpr int S = 2048, D = 128;
    __shared__ short Kh_s[64 * 128];    // swizzled, no pad
    __shared__ short Kl_s[64 * 128];
    __shared__ short Vt_s[128 * 64];    // swizzled, no pad
    __shared__ short P_s[128 * 72];     // per-wave 32-row slices, stride 64+8

    const int bh = blockIdx.y, b = bh >> 3, h = bh & 7;
    const int q0 = blockIdx.x * 128;
    const int t = threadIdx.x, wave = t >> 6, lane = t & 63;
    const int quad = lane >> 4, l16 = lane & 15;
    const int e8 = l16 & 7;             // xor-swizzle key

    // ones B-fragment: B[n=l16][k] = (n==0) ? 1.0bf16 : 0  -> C[., col0] = rowsum
    bf16x8 bones;
    {
        short o = (l16 == 0) ? (short)0x3F80 : (short)0;
        for (int j = 0; j < 8; ++j) bones[j] = o;
    }

    // Q fragments (A-layout A[m=l16][k=quad*8+j]), 2 m-blocks x 4 k-chunks
    bf16x8 qfh[2][4], qfl[2][4];
    for (int mb = 0; mb < 2; ++mb) {
        size_t qbase = ((size_t)(b * 8 + h) * S + q0 + wave * 32 + mb * 16 + l16) * D + quad * 8;
        for (int c = 0; c < 4; ++c) {
            qfh[mb][c] = *(const bf16x8*)(qh + qbase + c * 32);
            qfl[mb][c] = *(const bf16x8*)(ql + qbase + c * 32);
        }
    }

    float mrow[2][4];
    f32x4 oacc[2][8], lacc[2];
    for (int mb = 0; mb < 2; ++mb) {
        for (int r = 0; r < 4; ++r) mrow[mb][r] = -INFINITY;
        for (int oi = 0; oi < 8; ++oi) oacc[mb][oi] = (f32x4){0.f, 0.f, 0.f, 0.f};
        lacc[mb] = (f32x4){0.f, 0.f, 0.f, 0.f};
    }

    // R13 anti-phase: second dispatch round (the co-resident partner on each
    // CU) waits ~half an iteration once. Pure scheduling hint; no data dep.
    if (((blockIdx.x + (blockIdx.y << 4)) >> 8) & 1) {
        for (int i = 0; i < 13; ++i) __builtin_amdgcn_s_sleep(7);   // ~5.8k cyc
    }

    for (int kt = 0; kt < S / 64; ++kt) {
        __syncthreads();  // protect LDS reuse
        // --- stage K hi/lo: 64 rows x 128 ---
        {
            int pch = lane & 15;
            for (int i = 0; i < 4; ++i) {
                int rk = wave * 16 + i * 4 + (lane >> 4);
                int j = pch ^ (rk & 7);
                size_t g = ((size_t)b * S + kt * 64 + rk) * D + j * 8;
                int ldsoff = (wave * 16 + i * 4) * 128;
                __builtin_amdgcn_global_load_lds(GLB(kh + g), LDS(&Kh_s[ldsoff]), 16, 0, 0);
                __builtin_amdgcn_global_load_lds(GLB(kl + g), LDS(&Kl_s[ldsoff]), 16, 0, 0);
            }
        }
        // --- stage V^T: 128 rows(o) x 64(s) ---
        {
            int pch = lane & 7;
            for (int i = 0; i < 4; ++i) {
                int rv = wave * 32 + i * 8 + (lane >> 3);
                int j = pch ^ (rv & 7);
                size_t g = ((size_t)b * D + rv) * S + kt * 64 + j * 8;
                int ldsoff = (wave * 32 + i * 8) * 64;
                __builtin_amdgcn_global_load_lds(GLB(vt + g), LDS(&Vt_s[ldsoff]), 16, 0, 0);
            }
        }
        __syncthreads();

        // --- S' = Q' K^T (split: hh + lh + hl); scores already * scale*log2e ---
        f32x4 sacc[2][4];
        for (int mb = 0; mb < 2; ++mb)
            for (int ni = 0; ni < 4; ++ni) sacc[mb][ni] = (f32x4){0.f, 0.f, 0.f, 0.f};
        for (int ni = 0; ni < 4; ++ni) {
            for (int c = 0; c < 4; ++c) {
                int off = (ni * 16 + l16) * 128 + ((c * 4 + quad) ^ e8) * 8;
                bf16x8 kbh = *(const bf16x8*)&Kh_s[off];
                bf16x8 kbl = *(const bf16x8*)&Kl_s[off];
                __builtin_amdgcn_s_setprio(1);
                for (int mb = 0; mb < 2; ++mb) {
                    sacc[mb][ni] = MFMA(qfh[mb][c], kbh, sacc[mb][ni]);
                    sacc[mb][ni] = MFMA(qfl[mb][c], kbh, sacc[mb][ni]);
                    sacc[mb][ni] = MFMA(qfh[mb][c], kbl, sacc[mb][ni]);
                }
                __builtin_amdgcn_s_setprio(0);
            }
        }

        // --- online softmax (exp2 domain); rows quad*4+r per m-block ---
        for (int mb = 0; mb < 2; ++mb) {
            for (int r = 0; r < 4; ++r) {
                float mx = fmaxf(fmaxf(sacc[mb][0][r], sacc[mb][1][r]),
                                 fmaxf(sacc[mb][2][r], sacc[mb][3][r]));
                for (int off = 8; off; off >>= 1) mx = fmaxf(mx, __shfl_xor(mx, off));
                float mnew = fmaxf(mrow[mb][r], mx);
                float alpha = EXP2F(mrow[mb][r] - mnew);
                mrow[mb][r] = mnew;
                for (int ni = 0; ni < 4; ++ni)
                    sacc[mb][ni][r] = EXP2F(sacc[mb][ni][r] - mnew);
                lacc[mb][r] *= alpha;
                for (int oi = 0; oi < 8; ++oi) oacc[mb][oi][r] *= alpha;
            }
            // P -> LDS (C-layout -> A-layout); round-half-up bf16 (2 ops)
            for (int ni = 0; ni < 4; ++ni)
                for (int r = 0; r < 4; ++r) {
                    union { float f; unsigned u; } cv; cv.f = sacc[mb][ni][r];
                    P_s[(wave * 32 + mb * 16 + quad * 4 + r) * 72 + ni * 16 + l16] =
                        (short)((cv.u + 0x8000u) >> 16);
                }
        }

        // --- O += P @ V ; l += P @ ones (MFMA) ---
        for (int c2 = 0; c2 < 2; ++c2) {
            bf16x8 pa[2];
            for (int mb = 0; mb < 2; ++mb) {
                pa[mb] = *(const bf16x8*)&P_s[(wave * 32 + mb * 16 + l16) * 72 + c2 * 32 + quad * 8];
                lacc[mb] = MFMA(pa[mb], bones, lacc[mb]);
            }
            for (int oi = 0; oi < 8; ++oi) {
                int off = (oi * 16 + l16) * 64 + ((c2 * 4 + quad) ^ e8) * 8;
                bf16x8 vb = *(const bf16x8*)&Vt_s[off];
                __builtin_amdgcn_s_setprio(1);
                for (int mb = 0; mb < 2; ++mb)
                    oacc[mb][oi] = MFMA(pa[mb], vb, oacc[mb][oi]);
                __builtin_amdgcn_s_setprio(0);
            }
        }
    }

    // epilogue: ctx[b][s][h*128+o] bf16; l lives in col-0 lanes (l16==0)
    for (int mb = 0; mb < 2; ++mb) {
        for (int r = 0; r < 4; ++r) {
            float ls = __shfl(lacc[mb][r], lane & 48);  // broadcast from l16==0 of quad
            float inv = 1.f / ls;
            int s = q0 + wave * 32 + mb * 16 + quad * 4 + r;
            size_t base = ((size_t)b * S + s) * 1024 + h * 128;
            for (int oi = 0; oi < 8; ++oi)
                ctx[base + oi * 16 + l16] = f2bf(oacc[mb][oi][r] * inv);
        }
    }
}

// ---------------- launch ----------------

extern "C" void kernel_launch(void* const* d_in, const int* in_sizes, int n_in,
                              void* d_out, int out_size, void* d_ws, size_t ws_size,
                              hipStream_t stream) {
    const float* x  = (const float*)d_in[0];
    const float* Wq = (const float*)d_in[1];
    const float* Wk = (const float*)d_in[2];
    const float* Wv = (const float*)d_in[3];
    const float* Wo = (const float*)d_in[4];
    float* out = (float*)d_out;

    char* p = (char*)d_ws;
    auto alloc = [&](size_t bytes) { char* r = p; p += bytes; return r; };
    short* xh  = (short*)alloc(16777216);  // x hi    (8192 x 1024)
    short* xl  = (short*)alloc(16777216);  // x lo
    short* wth = (short*)alloc(2621440);   // Wt hi   (1280 x 1024)
    short* wtl = (short*)alloc(2621440);   // Wt lo
    short* wot = (short*)alloc(2097152);   // Wo^T    (1024 x 1024)
    short* qh  = (short*)alloc(16777216);  // Q hi    (B,H,S,D), pre-scaled
    short* ql  = (short*)alloc(16777216);  // Q lo
    short* kh  = (short*)alloc(2097152);   // K hi    (B,S,D)
    short* kl  = (short*)alloc(2097152);   // K lo
    short* vt  = (short*)alloc(2097152);   // V^T     (B,D,S)
    short* ctx = (short*)alloc(16777216);  // ctx     (B,S,H*D)

    split_kernel<<<dim3(2048), dim3(256), 0, stream>>>(x, xh, xl, 8192 * 1024);
    build_wt<<<dim3(1280), dim3(256), 0, stream>>>(Wq, Wk, Wv, wth, wtl);
    build_wot<<<dim3(1024), dim3(256), 0, stream>>>(Wo, wot);
    gemm_k<0><<<dim3(64, 10), dim3(256), 0, stream>>>(xh, xl, wth, wtl,
                                                      qh, ql, kh, kl, vt, nullptr);
    attn_k<<<dim3(16, 32), dim3(256), 0, stream>>>(qh, ql, kh, kl, vt, ctx);
    gemm_k<1><<<dim3(64, 8), dim3(256), 0, stream>>>(ctx, nullptr, wot, nullptr,
                                                     nullptr, nullptr, nullptr, nullptr,
                                                     nullptr, out);
}

// Round 11
// 345.997 us; speedup vs baseline: 1.1917x; 1.0375x over previous
//
#include <hip/hip_runtime.h>
#include <math.h>

// ---------------------------------------------------------------------------
// Attention: B=4, S=2048, E=1024, H=8, O=128 (fp32 in/out)
// Split-bf16 (hi+lo) MFMA for x->QK and QK^T (precision-critical), plain bf16
// for V / PV / ctx@Wo. Flash-attention (no S x S materialize).
// R1-R5: see history. R6: 2-barrier attn (369.8us total).
// R7/R8: barrier-free attn REGRESSED (latency-bound at 2 waves/SIMD).
// R9: R6 + setprio: attn 168.7us (Mfma 36/VALU 31/Occ 20.6). BEST attn.
// R10: dbuf+raw-barrier NEUTRAL -> not load latency.
// R11: 4-blocks/CU REGRESSED -> not occupancy.
// R12: defer-max NEUTRAL -> not softmax-VALU volume.
// R13/R14: anti-phase s_sleep NEUTRAL (attn 167.0, counters identical) ->
//     not pipe phase-conflict. gemm0 V-block lo-skip KEPT (-7.6us, 359.0).
//     attn = 825 TF issued-MFMA ~ m214 plain-HIP ceiling -> near floor.
//     Non-attn = 192us vs ~106us roofline sum: ~86us unaccounted. build_wt
//     reads Wq stride-512B uncoalesced; build_wot reads Wo stride-4KB
//     uncoalesced; split_kernel uses scalar 2B stores (G13 violations).
// R15: (a) drop neutral s_sleep; (b) build_wt/build_wot -> LDS-tile
//     transpose (coalesced loads, [32][33] pad, short2 stores); (c)
//     split_kernel float4/short4 vectorized. Numerics identical.
// R16/R17: identical re-submits of R15 (broker timeouts; never measured).
// ---------------------------------------------------------------------------

typedef __attribute__((ext_vector_type(8))) short bf16x8;   // 8 bf16 (4 VGPRs)
typedef __attribute__((ext_vector_type(4))) float f32x4;
typedef __attribute__((ext_vector_type(4))) short s16x4;

#define MFMA(a, b, c) __builtin_amdgcn_mfma_f32_16x16x32_bf16((a), (b), (c), 0, 0, 0)
#define GLB(p) ((const __attribute__((address_space(1))) void*)(p))
#define LDS(p) ((__attribute__((address_space(3))) void*)(p))

#if __has_builtin(__builtin_amdgcn_exp2f)
#define EXP2F(x) __builtin_amdgcn_exp2f(x)
#else
#define EXP2F(x) exp2f(x)
#endif

__device__ __forceinline__ short f2bf(float f) {
    union { float f; unsigned u; } v; v.f = f;
    unsigned r = v.u + 0x7fffu + ((v.u >> 16) & 1u);   // RNE
    return (short)(r >> 16);
}
__device__ __forceinline__ float bf2f(short s) {
    union { unsigned u; float f; } v; v.u = ((unsigned)(unsigned short)s) << 16;
    return v.f;
}

// ---------------- prep kernels (R15: coalesced) ----------------

__global__ __launch_bounds__(256) void split_kernel(
    const float* __restrict__ x, short* __restrict__ hi, short* __restrict__ lo, int n4) {
    for (int i = blockIdx.x * blockDim.x + threadIdx.x; i < n4; i += gridDim.x * blockDim.x) {
        f32x4 v = *(const f32x4*)&x[(size_t)i * 4];
        s16x4 h, l;
        for (int j = 0; j < 4; ++j) {
            float f = v[j];
            short hh = f2bf(f);
            h[j] = hh;
            l[j] = f2bf(f - bf2f(hh));
        }
        *(s16x4*)&hi[(size_t)i * 4] = h;
        *(s16x4*)&lo[(size_t)i * 4] = l;
    }
}

// Wt[n][k] (n = 8 Wq-heads' o | Wk o | Wv o): LDS-tile transpose of the
// [k][o]-major sources. grid (32 ktiles, 4 otiles, 10 mats).
__global__ __launch_bounds__(256) void build_wt(
    const float* __restrict__ Wq, const float* __restrict__ Wk, const float* __restrict__ Wv,
    short* __restrict__ wth, short* __restrict__ wtl) {
    __shared__ float tile[32][33];
    const int m = blockIdx.z;
    const int k0 = blockIdx.x * 32, o0 = blockIdx.y * 32;
    const float* src = (m < 8) ? (Wq + (size_t)m * 1024 * 128) : (m == 8 ? Wk : Wv);
    const int base_n = (m < 8) ? m * 128 : (m == 8 ? 1024 : 1152);
    const int t = threadIdx.x;
    {
        int tx = t & 31, ty = t >> 5;               // coalesced [k][o] loads
        for (int p = 0; p < 4; ++p)
            tile[ty + p * 8][tx] = src[(size_t)(k0 + ty + p * 8) * 128 + o0 + tx];
    }
    __syncthreads();
    {
        int kx = (t & 15) * 2, oy = t >> 4;         // coalesced [n][k] stores
        for (int p = 0; p < 2; ++p) {
            int o = oy + p * 16;
            float f0 = tile[kx][o], f1 = tile[kx + 1][o];
            short h0 = f2bf(f0), h1 = f2bf(f1);
            short l0 = f2bf(f0 - bf2f(h0)), l1 = f2bf(f1 - bf2f(h1));
            size_t oidx = (size_t)(base_n + o0 + o) * 1024 + k0 + kx;
            *(unsigned*)&wth[oidx] = (unsigned)(unsigned short)h0 |
                                     ((unsigned)(unsigned short)h1 << 16);
            *(unsigned*)&wtl[oidx] = (unsigned)(unsigned short)l0 |
                                     ((unsigned)(unsigned short)l1 << 16);
        }
    }
}

// wot[e][k] = bf16(Wo[k][e]): LDS-tile transpose. grid (32, 32).
__global__ __launch_bounds__(256) void build_wot(
    const float* __restrict__ Wo, short* __restrict__ wot) {
    __shared__ float tile[32][33];
    const int k0 = blockIdx.x * 32, e0 = blockIdx.y * 32;
    const int t = threadIdx.x;
    {
        int tx = t & 31, ty = t >> 5;
        for (int p = 0; p < 4; ++p)
            tile[ty + p * 8][tx] = Wo[(size_t)(k0 + ty + p * 8) * 1024 + e0 + tx];
    }
    __syncthreads();
    {
        int kx = (t & 15) * 2, ey = t >> 4;
        for (int p = 0; p < 2; ++p) {
            int e = ey + p * 16;
            float f0 = tile[kx][e], f1 = tile[kx + 1][e];
            short h0 = f2bf(f0), h1 = f2bf(f1);
            size_t oidx = (size_t)(e0 + e) * 1024 + k0 + kx;
            *(unsigned*)&wot[oidx] = (unsigned)(unsigned short)h0 |
                                     ((unsigned)(unsigned short)h1 << 16);
        }
    }
}

// ---------------- GEMM: C(M x N) = A(M x 1024) @ Bt(N x 1024)^T ----------------
// K-tiles and epilogue staging share one LDS allocation (disjoint lifetimes,
// barrier-separated): 33.8 KB -> 4 blocks/CU.
// y==9 (V block) only consumes the hi result -> skip lo staging + lo MFMAs.
template <int MODE>
__global__ __launch_bounds__(256, 4) void gemm_k(
    const short* __restrict__ Ah, const short* __restrict__ Al,
    const short* __restrict__ Bth, const short* __restrict__ Btl,
    short* __restrict__ qh, short* __restrict__ ql,
    short* __restrict__ kh, short* __restrict__ kl,
    short* __restrict__ vt, float* __restrict__ outf) {
    constexpr int K = 1024;
    __shared__ __align__(16) char smem[33792];
    short* As_h = (short*)smem;                 // 128x32 = 8192 B
    short* Bs_h = (short*)(smem + 8192);
    short* As_l = (short*)(smem + 16384);       // MODE 0 only
    short* Bs_l = (short*)(smem + 24576);
    unsigned* Ep = (unsigned*)smem;             // 64x132 u32 = 33792 B (epilogue)

    const int t = threadIdx.x;
    const int m0 = blockIdx.x * 128, n0 = blockIdx.y * 128;
    const int wave = t >> 6, lane = t & 63;
    const int wr = wave >> 1, wc = wave & 1;
    const int quad = lane >> 4, l16 = lane & 15;
    const bool needLo = (MODE == 0) && (blockIdx.y < 9);   // V block skips lo

    f32x4 acc[4][4];
    for (int i = 0; i < 4; ++i)
        for (int j = 0; j < 4; ++j) acc[i][j] = (f32x4){0.f, 0.f, 0.f, 0.f};

    for (int kb = 0; kb < K / 32; ++kb) {
        __syncthreads();
        // DMA staging: each matrix = 512 slots of 16 B; 2 wave-insts per wave.
        for (int i = 0; i < 2; ++i) {
            int slot = (wave * 2 + i) * 64 + lane;
            int row = slot >> 2, ch = slot & 3;
            int ldsoff = (wave * 2 + i) * 512;  // shorts; +lane*16B by HW
            size_t ga = (size_t)(m0 + row) * K + kb * 32 + ch * 8;
            size_t gb = (size_t)(n0 + row) * K + kb * 32 + ch * 8;
            __builtin_amdgcn_global_load_lds(GLB(Ah + ga), LDS(&As_h[ldsoff]), 16, 0, 0);
            __builtin_amdgcn_global_load_lds(GLB(Bth + gb), LDS(&Bs_h[ldsoff]), 16, 0, 0);
            if constexpr (MODE == 0) {
                if (needLo) {
                    __builtin_amdgcn_global_load_lds(GLB(Al + ga), LDS(&As_l[ldsoff]), 16, 0, 0);
                    __builtin_amdgcn_global_load_lds(GLB(Btl + gb), LDS(&Bs_l[ldsoff]), 16, 0, 0);
                }
            }
        }
        __syncthreads();

        bf16x8 a[4], b[4];
        for (int mi = 0; mi < 4; ++mi)
            a[mi] = *(const bf16x8*)&As_h[(wr * 64 + mi * 16 + l16) * 32 + quad * 8];
        for (int ni = 0; ni < 4; ++ni)
            b[ni] = *(const bf16x8*)&Bs_h[(wc * 64 + ni * 16 + l16) * 32 + quad * 8];
        for (int mi = 0; mi < 4; ++mi)
            for (int ni = 0; ni < 4; ++ni)
                acc[mi][ni] = MFMA(a[mi], b[ni], acc[mi][ni]);
        if constexpr (MODE == 0) {
            if (needLo) {
                bf16x8 al[4], bl[4];
                for (int mi = 0; mi < 4; ++mi)
                    al[mi] = *(const bf16x8*)&As_l[(wr * 64 + mi * 16 + l16) * 32 + quad * 8];
                for (int ni = 0; ni < 4; ++ni)
                    bl[ni] = *(const bf16x8*)&Bs_l[(wc * 64 + ni * 16 + l16) * 32 + quad * 8];
                for (int mi = 0; mi < 4; ++mi)
                    for (int ni = 0; ni < 4; ++ni) {
                        acc[mi][ni] = MFMA(a[mi], bl[ni], acc[mi][ni]);
                        acc[mi][ni] = MFMA(al[mi], b[ni], acc[mi][ni]);
                    }
            }
        }
    }

    // LDS-staged epilogue (C/D layout: col=l16, row=quad*4+r).
    // Q columns pre-scaled by (1/sqrt(128))*log2(e) for exp2-domain softmax.
    const float qscale = 0.12753102455195157f;
    for (int p = 0; p < 2; ++p) {
        __syncthreads();   // also separates K-loop tile reads from Ep writes
        if (wr == p) {
            for (int mi = 0; mi < 4; ++mi) {
                int rl = mi * 16 + quad * 4;
                for (int ni = 0; ni < 4; ++ni) {
                    int cl = wc * 64 + ni * 16 + l16;
                    for (int r = 0; r < 4; ++r) {
                        float v = acc[mi][ni][r];
                        unsigned pk;
                        if constexpr (MODE == 0) {
                            if (blockIdx.y < 8) v *= qscale;
                            short hv = f2bf(v);
                            short lv = f2bf(v - bf2f(hv));
                            pk = (unsigned)(unsigned short)hv |
                                 ((unsigned)(unsigned short)lv << 16);
                        } else {
                            union { float f; unsigned u; } cv; cv.f = v; pk = cv.u;
                        }
                        Ep[(rl + r) * 132 + cl] = pk;
                    }
                }
            }
        }
        __syncthreads();

        if constexpr (MODE == 1) {
            for (int j = 0; j < 8; ++j) {
                int cid = t + j * 256;
                int row = cid >> 5, c = cid & 31;
                f32x4 val;
                for (int q = 0; q < 4; ++q) {
                    union { unsigned u; float f; } cv;
                    cv.u = Ep[row * 132 + c * 4 + q];
                    val[q] = cv.f;
                }
                int gr = m0 + p * 64 + row;
                *(f32x4*)&outf[(size_t)gr * 1024 + n0 + c * 4] = val;
            }
        } else if (blockIdx.y < 9) {
            for (int j = 0; j < 4; ++j) {
                int cid = t + j * 256;
                int row = cid >> 4, c = cid & 15;
                bf16x8 hv, lv;
                for (int q = 0; q < 8; ++q) {
                    unsigned w = Ep[row * 132 + c * 8 + q];
                    hv[q] = (short)(w & 0xffffu);
                    lv[q] = (short)(w >> 16);
                }
                int gr = m0 + p * 64 + row;
                int bb = gr >> 11, s = gr & 2047;
                if (blockIdx.y < 8) {
                    size_t base = (((size_t)(bb * 8 + (n0 >> 7))) * 2048 + s) * 128 + c * 8;
                    *(bf16x8*)&qh[base] = hv;
                    *(bf16x8*)&ql[base] = lv;
                } else {
                    size_t base = ((size_t)bb * 2048 + s) * 128 + c * 8;
                    *(bf16x8*)&kh[base] = hv;
                    *(bf16x8*)&kl[base] = lv;
                }
            }
        } else {
            for (int j = 0; j < 4; ++j) {
                int cid = t + j * 256;
                int d = cid >> 3, sc = cid & 7;
                bf16x8 hv;
                for (int q = 0; q < 8; ++q) {
                    unsigned w = Ep[(sc * 8 + q) * 132 + d];
                    hv[q] = (short)(w & 0xffffu);
                }
                int gr0 = m0 + p * 64 + sc * 8;
                int bb = gr0 >> 11, s0 = gr0 & 2047;
                *(bf16x8*)&vt[((size_t)bb * 128 + d) * 2048 + s0] = hv;
            }
        }
    }
}

// ---------------- flash attention (R9 structure, verified best) ----------------
// grid (S/128, B*H); 4 waves x 32 query rows (2 m-blocks); BN=64 keys/iter.
// K/V staged via global_load_lds with XOR-swizzled chunks between the two
// barriers (single drain point; wave-level overlap hides the rest).
// setprio(1) around MFMA clusters (kept from R9). s_sleep removed (neutral).
__global__ __launch_bounds__(256, 2) void attn_k(
    const short* __restrict__ qh, const short* __restrict__ ql,
    const short* __restrict__ kh, const short* __restrict__ kl,
    const short* __restrict__ vt, short* __restrict__ ctx) {
    constexpr int S = 2048, D = 128;
    __shared__ short Kh_s[64 * 128];    // swizzled, no pad
    __shared__ short Kl_s[64 * 128];
    __shared__ short Vt_s[128 * 64];    // swizzled, no pad
    __shared__ short P_s[128 * 72];     // per-wave 32-row slices, stride 64+8

    const int bh = blockIdx.y, b = bh >> 3, h = bh & 7;
    const int q0 = blockIdx.x * 128;
    const int t = threadIdx.x, wave = t >> 6, lane = t & 63;
    const int quad = lane >> 4, l16 = lane & 15;
    const int e8 = l16 & 7;             // xor-swizzle key

    // ones B-fragment: B[n=l16][k] = (n==0) ? 1.0bf16 : 0  -> C[., col0] = rowsum
    bf16x8 bones;
    {
        short o = (l16 == 0) ? (short)0x3F80 : (short)0;
        for (int j = 0; j < 8; ++j) bones[j] = o;
    }

    // Q fragments (A-layout A[m=l16][k=quad*8+j]), 2 m-blocks x 4 k-chunks
    bf16x8 qfh[2][4], qfl[2][4];
    for (int mb = 0; mb < 2; ++mb) {
        size_t qbase = ((size_t)(b * 8 + h) * S + q0 + wave * 32 + mb * 16 + l16) * D + quad * 8;
        for (int c = 0; c < 4; ++c) {
            qfh[mb][c] = *(const bf16x8*)(qh + qbase + c * 32);
            qfl[mb][c] = *(const bf16x8*)(ql + qbase + c * 32);
        }
    }

    float mrow[2][4];
    f32x4 oacc[2][8], lacc[2];
    for (int mb = 0; mb < 2; ++mb) {
        for (int r = 0; r < 4; ++r) mrow[mb][r] = -INFINITY;
        for (int oi = 0; oi < 8; ++oi) oacc[mb][oi] = (f32x4){0.f, 0.f, 0.f, 0.f};
        lacc[mb] = (f32x4){0.f, 0.f, 0.f, 0.f};
    }

    for (int kt = 0; kt < S / 64; ++kt) {
        __syncthreads();  // protect LDS reuse
        // --- stage K hi/lo: 64 rows x 128 ---
        {
            int pch = lane & 15;
            for (int i = 0; i < 4; ++i) {
                int rk = wave * 16 + i * 4 + (lane >> 4);
                int j = pch ^ (rk & 7);
                size_t g = ((size_t)b * S + kt * 64 + rk) * D + j * 8;
                int ldsoff = (wave * 16 + i * 4) * 128;
                __builtin_amdgcn_global_load_lds(GLB(kh + g), LDS(&Kh_s[ldsoff]), 16, 0, 0);
                __builtin_amdgcn_global_load_lds(GLB(kl + g), LDS(&Kl_s[ldsoff]), 16, 0, 0);
            }
        }
        // --- stage V^T: 128 rows(o) x 64(s) ---
        {
            int pch = lane & 7;
            for (int i = 0; i < 4; ++i) {
                int rv = wave * 32 + i * 8 + (lane >> 3);
                int j = pch ^ (rv & 7);
                size_t g = ((size_t)b * D + rv) * S + kt * 64 + j * 8;
                int ldsoff = (wave * 32 + i * 8) * 64;
                __builtin_amdgcn_global_load_lds(GLB(vt + g), LDS(&Vt_s[ldsoff]), 16, 0, 0);
            }
        }
        __syncthreads();

        // --- S' = Q' K^T (split: hh + lh + hl); scores already * scale*log2e ---
        f32x4 sacc[2][4];
        for (int mb = 0; mb < 2; ++mb)
            for (int ni = 0; ni < 4; ++ni) sacc[mb][ni] = (f32x4){0.f, 0.f, 0.f, 0.f};
        for (int ni = 0; ni < 4; ++ni) {
            for (int c = 0; c < 4; ++c) {
                int off = (ni * 16 + l16) * 128 + ((c * 4 + quad) ^ e8) * 8;
                bf16x8 kbh = *(const bf16x8*)&Kh_s[off];
                bf16x8 kbl = *(const bf16x8*)&Kl_s[off];
                __builtin_amdgcn_s_setprio(1);
                for (int mb = 0; mb < 2; ++mb) {
                    sacc[mb][ni] = MFMA(qfh[mb][c], kbh, sacc[mb][ni]);
                    sacc[mb][ni] = MFMA(qfl[mb][c], kbh, sacc[mb][ni]);
                    sacc[mb][ni] = MFMA(qfh[mb][c], kbl, sacc[mb][ni]);
                }
                __builtin_amdgcn_s_setprio(0);
            }
        }

        // --- online softmax (exp2 domain); rows quad*4+r per m-block ---
        for (int mb = 0; mb < 2; ++mb) {
            for (int r = 0; r < 4; ++r) {
                float mx = fmaxf(fmaxf(sacc[mb][0][r], sacc[mb][1][r]),
                                 fmaxf(sacc[mb][2][r], sacc[mb][3][r]));
                for (int off = 8; off; off >>= 1) mx = fmaxf(mx, __shfl_xor(mx, off));
                float mnew = fmaxf(mrow[mb][r], mx);
                float alpha = EXP2F(mrow[mb][r] - mnew);
                mrow[mb][r] = mnew;
                for (int ni = 0; ni < 4; ++ni)
                    sacc[mb][ni][r] = EXP2F(sacc[mb][ni][r] - mnew);
                lacc[mb][r] *= alpha;
                for (int oi = 0; oi < 8; ++oi) oacc[mb][oi][r] *= alpha;
            }
            // P -> LDS (C-layout -> A-layout); round-half-up bf16 (2 ops)
            for (int ni = 0; ni < 4; ++ni)
                for (int r = 0; r < 4; ++r) {
                    union { float f; unsigned u; } cv; cv.f = sacc[mb][ni][r];
                    P_s[(wave * 32 + mb * 16 + quad * 4 + r) * 72 + ni * 16 + l16] =
                        (short)((cv.u + 0x8000u) >> 16);
                }
        }

        // --- O += P @ V ; l += P @ ones (MFMA) ---
        for (int c2 = 0; c2 < 2; ++c2) {
            bf16x8 pa[2];
            for (int mb = 0; mb < 2; ++mb) {
                pa[mb] = *(const bf16x8*)&P_s[(wave * 32 + mb * 16 + l16) * 72 + c2 * 32 + quad * 8];
                lacc[mb] = MFMA(pa[mb], bones, lacc[mb]);
            }
            for (int oi = 0; oi < 8; ++oi) {
                int off = (oi * 16 + l16) * 64 + ((c2 * 4 + quad) ^ e8) * 8;
                bf16x8 vb = *(const bf16x8*)&Vt_s[off];
                __builtin_amdgcn_s_setprio(1);
                for (int mb = 0; mb < 2; ++mb)
                    oacc[mb][oi] = MFMA(pa[mb], vb, oacc[mb][oi]);
                __builtin_amdgcn_s_setprio(0);
            }
        }
    }

    // epilogue: ctx[b][s][h*128+o] bf16; l lives in col-0 lanes (l16==0)
    for (int mb = 0; mb < 2; ++mb) {
        for (int r = 0; r < 4; ++r) {
            float ls = __shfl(lacc[mb][r], lane & 48);  // broadcast from l16==0 of quad
            float inv = 1.f / ls;
            int s = q0 + wave * 32 + mb * 16 + quad * 4 + r;
            size_t base = ((size_t)b * S + s) * 1024 + h * 128;
            for (int oi = 0; oi < 8; ++oi)
                ctx[base + oi * 16 + l16] = f2bf(oacc[mb][oi][r] * inv);
        }
    }
}

// ---------------- launch ----------------

extern "C" void kernel_launch(void* const* d_in, const int* in_sizes, int n_in,
                              void* d_out, int out_size, void* d_ws, size_t ws_size,
                              hipStream_t stream) {
    const float* x  = (const float*)d_in[0];
    const float* Wq = (const float*)d_in[1];
    const float* Wk = (const float*)d_in[2];
    const float* Wv = (const float*)d_in[3];
    const float* Wo = (const float*)d_in[4];
    float* out = (float*)d_out;

    char* p = (char*)d_ws;
    auto alloc = [&](size_t bytes) { char* r = p; p += bytes; return r; };
    short* xh  = (short*)alloc(16777216);  // x hi    (8192 x 1024)
    short* xl  = (short*)alloc(16777216);  // x lo
    short* wth = (short*)alloc(2621440);   // Wt hi   (1280 x 1024)
    short* wtl = (short*)alloc(2621440);   // Wt lo
    short* wot = (short*)alloc(2097152);   // Wo^T    (1024 x 1024)
    short* qh  = (short*)alloc(16777216);  // Q hi    (B,H,S,D), pre-scaled
    short* ql  = (short*)alloc(16777216);  // Q lo
    short* kh  = (short*)alloc(2097152);   // K hi    (B,S,D)
    short* kl  = (short*)alloc(2097152);   // K lo
    short* vt  = (short*)alloc(2097152);   // V^T     (B,D,S)
    short* ctx = (short*)alloc(16777216);  // ctx     (B,S,H*D)

    split_kernel<<<dim3(2048), dim3(256), 0, stream>>>(x, xh, xl, 8192 * 1024 / 4);
    build_wt<<<dim3(32, 4, 10), dim3(256), 0, stream>>>(Wq, Wk, Wv, wth, wtl);
    build_wot<<<dim3(32, 32), dim3(256), 0, stream>>>(Wo, wot);
    gemm_k<0><<<dim3(64, 10), dim3(256), 0, stream>>>(xh, xl, wth, wtl,
                                                      qh, ql, kh, kl, vt, nullptr);
    attn_k<<<dim3(16, 32), dim3(256), 0, stream>>>(qh, ql, kh, kl, vt, ctx);
    gemm_k<1><<<dim3(64, 8), dim3(256), 0, stream>>>(ctx, nullptr, wot, nullptr,
                                                     nullptr, nullptr, nullptr, nullptr,
                                                     nullptr, out);
}

// Round 17
// 336.062 us; speedup vs baseline: 1.2269x; 1.0296x over previous
//
#include <hip/hip_runtime.h>
#include <math.h>

// ---------------------------------------------------------------------------
// Attention: B=4, S=2048, E=1024, H=8, O=128 (fp32 in/out)
// Split-bf16 (hi+lo) MFMA for x->QK and QK^T (precision-critical), plain bf16
// for V / PV / ctx@Wo. Flash-attention (no S x S materialize).
// R1-R5: see history. R6: 2-barrier attn (369.8us total).
// R7/R8: barrier-free attn REGRESSED (latency-bound at 2 waves/SIMD).
// R9: R6 + setprio: attn 168.7us (Mfma 36/VALU 31/Occ 20.6). BEST attn.
// R10: dbuf+raw-barrier NEUTRAL -> not load latency.
// R11: 4-blocks/CU REGRESSED -> not occupancy.
// R12: defer-max NEUTRAL -> not softmax-VALU volume.
// R13/R14: anti-phase NEUTRAL. gemm0 V-block lo-skip KEPT (-7.6us, 359.0).
// R15-R17: coalesced preps KEPT (-13us, 346.0; attn control unchanged).
//     Non-attn now 179us vs ~118us roofline(+gaps) -> ~60us inside gemms.
//     Theory: default round-robin dispatch spreads the 10 column-blocks
//     sharing each A-panel across XCDs -> A's 10x reuse served by L3/HBM
//     (per-XCD touched set ~72 MB). T1 mechanism applies.
// R18: (1) XCD-clustered remap inside gemm_k: XCD c owns x === c (mod 8)
//     x all y -> per-XCD set ~13 MB, A-reuse becomes L2-hits. Bijective:
//     g=L/(8*NY), r=L%(8*NY), x=g*8+(r&7), y=r>>3. (2) preps fused into
//     one dispatch (-2 launch gaps). Attn untouched as control.
// R19-R23: identical re-submits of R18 (6x infra failures; never measured).
//     Kernel audited clean (OOB/sync); experiment remains open on record.
// ---------------------------------------------------------------------------

typedef __attribute__((ext_vector_type(8))) short bf16x8;   // 8 bf16 (4 VGPRs)
typedef __attribute__((ext_vector_type(4))) float f32x4;
typedef __attribute__((ext_vector_type(4))) short s16x4;

#define MFMA(a, b, c) __builtin_amdgcn_mfma_f32_16x16x32_bf16((a), (b), (c), 0, 0, 0)
#define GLB(p) ((const __attribute__((address_space(1))) void*)(p))
#define LDS(p) ((__attribute__((address_space(3))) void*)(p))

#if __has_builtin(__builtin_amdgcn_exp2f)
#define EXP2F(x) __builtin_amdgcn_exp2f(x)
#else
#define EXP2F(x) exp2f(x)
#endif

__device__ __forceinline__ short f2bf(float f) {
    union { float f; unsigned u; } v; v.f = f;
    unsigned r = v.u + 0x7fffu + ((v.u >> 16) & 1u);   // RNE
    return (short)(r >> 16);
}
__device__ __forceinline__ float bf2f(short s) {
    union { unsigned u; float f; } v; v.u = ((unsigned)(unsigned short)s) << 16;
    return v.f;
}

// ---------------- fused prep kernel (R18) ----------------
// blocks [0,2048): x -> xh/xl split (float4/short4 vectorized)
// blocks [2048,3328): Wq/Wk/Wv -> Wt transpose (LDS tile, coalesced)
// blocks [3328,4352): Wo -> Wo^T bf16 transpose (LDS tile, coalesced)
__global__ __launch_bounds__(256) void prep_all(
    const float* __restrict__ x, short* __restrict__ xh, short* __restrict__ xl,
    const float* __restrict__ Wq, const float* __restrict__ Wk,
    const float* __restrict__ Wv, short* __restrict__ wth, short* __restrict__ wtl,
    const float* __restrict__ Wo, short* __restrict__ wot) {
    __shared__ float tile[32][33];
    const int bid = blockIdx.x, t = threadIdx.x;

    if (bid < 2048) {
        for (int i = bid * 256 + t; i < 2097152; i += 2048 * 256) {
            f32x4 v = *(const f32x4*)&x[(size_t)i * 4];
            s16x4 h, l;
            for (int j = 0; j < 4; ++j) {
                float f = v[j];
                short hh = f2bf(f);
                h[j] = hh;
                l[j] = f2bf(f - bf2f(hh));
            }
            *(s16x4*)&xh[(size_t)i * 4] = h;
            *(s16x4*)&xl[(size_t)i * 4] = l;
        }
        return;
    }

    if (bid < 3328) {
        const int l = bid - 2048;                   // old grid (32,4,10)
        const int m = l / 128, rem = l % 128;
        const int o0 = (rem / 32) * 32, k0 = (rem % 32) * 32;
        const float* src = (m < 8) ? (Wq + (size_t)m * 1024 * 128) : (m == 8 ? Wk : Wv);
        const int base_n = (m < 8) ? m * 128 : (m == 8 ? 1024 : 1152);
        {
            int tx = t & 31, ty = t >> 5;           // coalesced [k][o] loads
            for (int p = 0; p < 4; ++p)
                tile[ty + p * 8][tx] = src[(size_t)(k0 + ty + p * 8) * 128 + o0 + tx];
        }
        __syncthreads();
        {
            int kx = (t & 15) * 2, oy = t >> 4;     // coalesced [n][k] stores
            for (int p = 0; p < 2; ++p) {
                int o = oy + p * 16;
                float f0 = tile[kx][o], f1 = tile[kx + 1][o];
                short h0 = f2bf(f0), h1 = f2bf(f1);
                short l0 = f2bf(f0 - bf2f(h0)), l1 = f2bf(f1 - bf2f(h1));
                size_t oidx = (size_t)(base_n + o0 + o) * 1024 + k0 + kx;
                *(unsigned*)&wth[oidx] = (unsigned)(unsigned short)h0 |
                                         ((unsigned)(unsigned short)h1 << 16);
                *(unsigned*)&wtl[oidx] = (unsigned)(unsigned short)l0 |
                                         ((unsigned)(unsigned short)l1 << 16);
            }
        }
        return;
    }

    {
        const int l = bid - 3328;                   // old grid (32,32)
        const int k0 = (l & 31) * 32, e0 = (l >> 5) * 32;
        {
            int tx = t & 31, ty = t >> 5;
            for (int p = 0; p < 4; ++p)
                tile[ty + p * 8][tx] = Wo[(size_t)(k0 + ty + p * 8) * 1024 + e0 + tx];
        }
        __syncthreads();
        {
            int kx = (t & 15) * 2, ey = t >> 4;
            for (int p = 0; p < 2; ++p) {
                int e = ey + p * 16;
                float f0 = tile[kx][e], f1 = tile[kx + 1][e];
                short h0 = f2bf(f0), h1 = f2bf(f1);
                size_t oidx = (size_t)(e0 + e) * 1024 + k0 + kx;
                *(unsigned*)&wot[oidx] = (unsigned)(unsigned short)h0 |
                                         ((unsigned)(unsigned short)h1 << 16);
            }
        }
    }
}

// ---------------- GEMM: C(M x N) = A(M x 1024) @ Bt(N x 1024)^T ----------------
// K-tiles and epilogue staging share one LDS allocation (disjoint lifetimes,
// barrier-separated): 33.8 KB -> 4 blocks/CU.
// y==9 (V block) only consumes the hi result -> skip lo staging + lo MFMAs.
// R18: XCD-clustered remap: hw id L (=x'+gdim.x*y'), XCD = L%8; assign
// bx = (L/(8*NY))*8 + (L%(8*NY))&7, by = (L%(8*NY))>>3 -> XCD c owns
// bx===c(mod 8) x all by: its 10(8) blocks share 8 A-panels + B in L2.
template <int MODE>
__global__ __launch_bounds__(256, 4) void gemm_k(
    const short* __restrict__ Ah, const short* __restrict__ Al,
    const short* __restrict__ Bth, const short* __restrict__ Btl,
    short* __restrict__ qh, short* __restrict__ ql,
    short* __restrict__ kh, short* __restrict__ kl,
    short* __restrict__ vt, float* __restrict__ outf) {
    constexpr int K = 1024;
    constexpr int NY = (MODE == 0) ? 10 : 8;
    __shared__ __align__(16) char smem[33792];
    short* As_h = (short*)smem;                 // 128x32 = 8192 B
    short* Bs_h = (short*)(smem + 8192);
    short* As_l = (short*)(smem + 16384);       // MODE 0 only
    short* Bs_l = (short*)(smem + 24576);
    unsigned* Ep = (unsigned*)smem;             // 64x132 u32 = 33792 B (epilogue)

    const int t = threadIdx.x;
    const int L = blockIdx.y * gridDim.x + blockIdx.x;
    const int rg = L / (8 * NY), rr = L % (8 * NY);
    const int bx = rg * 8 + (rr & 7), by = rr >> 3;
    const int m0 = bx * 128, n0 = by * 128;
    const int wave = t >> 6, lane = t & 63;
    const int wr = wave >> 1, wc = wave & 1;
    const int quad = lane >> 4, l16 = lane & 15;
    const bool needLo = (MODE == 0) && (by < 9);   // V block skips lo

    f32x4 acc[4][4];
    for (int i = 0; i < 4; ++i)
        for (int j = 0; j < 4; ++j) acc[i][j] = (f32x4){0.f, 0.f, 0.f, 0.f};

    for (int kb = 0; kb < K / 32; ++kb) {
        __syncthreads();
        // DMA staging: each matrix = 512 slots of 16 B; 2 wave-insts per wave.
        for (int i = 0; i < 2; ++i) {
            int slot = (wave * 2 + i) * 64 + lane;
            int row = slot >> 2, ch = slot & 3;
            int ldsoff = (wave * 2 + i) * 512;  // shorts; +lane*16B by HW
            size_t ga = (size_t)(m0 + row) * K + kb * 32 + ch * 8;
            size_t gb = (size_t)(n0 + row) * K + kb * 32 + ch * 8;
            __builtin_amdgcn_global_load_lds(GLB(Ah + ga), LDS(&As_h[ldsoff]), 16, 0, 0);
            __builtin_amdgcn_global_load_lds(GLB(Bth + gb), LDS(&Bs_h[ldsoff]), 16, 0, 0);
            if constexpr (MODE == 0) {
                if (needLo) {
                    __builtin_amdgcn_global_load_lds(GLB(Al + ga), LDS(&As_l[ldsoff]), 16, 0, 0);
                    __builtin_amdgcn_global_load_lds(GLB(Btl + gb), LDS(&Bs_l[ldsoff]), 16, 0, 0);
                }
            }
        }
        __syncthreads();

        bf16x8 a[4], b[4];
        for (int mi = 0; mi < 4; ++mi)
            a[mi] = *(const bf16x8*)&As_h[(wr * 64 + mi * 16 + l16) * 32 + quad * 8];
        for (int ni = 0; ni < 4; ++ni)
            b[ni] = *(const bf16x8*)&Bs_h[(wc * 64 + ni * 16 + l16) * 32 + quad * 8];
        for (int mi = 0; mi < 4; ++mi)
            for (int ni = 0; ni < 4; ++ni)
                acc[mi][ni] = MFMA(a[mi], b[ni], acc[mi][ni]);
        if constexpr (MODE == 0) {
            if (needLo) {
                bf16x8 al[4], bl[4];
                for (int mi = 0; mi < 4; ++mi)
                    al[mi] = *(const bf16x8*)&As_l[(wr * 64 + mi * 16 + l16) * 32 + quad * 8];
                for (int ni = 0; ni < 4; ++ni)
                    bl[ni] = *(const bf16x8*)&Bs_l[(wc * 64 + ni * 16 + l16) * 32 + quad * 8];
                for (int mi = 0; mi < 4; ++mi)
                    for (int ni = 0; ni < 4; ++ni) {
                        acc[mi][ni] = MFMA(a[mi], bl[ni], acc[mi][ni]);
                        acc[mi][ni] = MFMA(al[mi], b[ni], acc[mi][ni]);
                    }
            }
        }
    }

    // LDS-staged epilogue (C/D layout: col=l16, row=quad*4+r).
    // Q columns pre-scaled by (1/sqrt(128))*log2(e) for exp2-domain softmax.
    const float qscale = 0.12753102455195157f;
    for (int p = 0; p < 2; ++p) {
        __syncthreads();   // also separates K-loop tile reads from Ep writes
        if (wr == p) {
            for (int mi = 0; mi < 4; ++mi) {
                int rl = mi * 16 + quad * 4;
                for (int ni = 0; ni < 4; ++ni) {
                    int cl = wc * 64 + ni * 16 + l16;
                    for (int r = 0; r < 4; ++r) {
                        float v = acc[mi][ni][r];
                        unsigned pk;
                        if constexpr (MODE == 0) {
                            if (by < 8) v *= qscale;
                            short hv = f2bf(v);
                            short lv = f2bf(v - bf2f(hv));
                            pk = (unsigned)(unsigned short)hv |
                                 ((unsigned)(unsigned short)lv << 16);
                        } else {
                            union { float f; unsigned u; } cv; cv.f = v; pk = cv.u;
                        }
                        Ep[(rl + r) * 132 + cl] = pk;
                    }
                }
            }
        }
        __syncthreads();

        if constexpr (MODE == 1) {
            for (int j = 0; j < 8; ++j) {
                int cid = t + j * 256;
                int row = cid >> 5, c = cid & 31;
                f32x4 val;
                for (int q = 0; q < 4; ++q) {
                    union { unsigned u; float f; } cv;
                    cv.u = Ep[row * 132 + c * 4 + q];
                    val[q] = cv.f;
                }
                int gr = m0 + p * 64 + row;
                *(f32x4*)&outf[(size_t)gr * 1024 + n0 + c * 4] = val;
            }
        } else if (by < 9) {
            for (int j = 0; j < 4; ++j) {
                int cid = t + j * 256;
                int row = cid >> 4, c = cid & 15;
                bf16x8 hv, lv;
                for (int q = 0; q < 8; ++q) {
                    unsigned w = Ep[row * 132 + c * 8 + q];
                    hv[q] = (short)(w & 0xffffu);
                    lv[q] = (short)(w >> 16);
                }
                int gr = m0 + p * 64 + row;
                int bb = gr >> 11, s = gr & 2047;
                if (by < 8) {
                    size_t base = (((size_t)(bb * 8 + (n0 >> 7))) * 2048 + s) * 128 + c * 8;
                    *(bf16x8*)&qh[base] = hv;
                    *(bf16x8*)&ql[base] = lv;
                } else {
                    size_t base = ((size_t)bb * 2048 + s) * 128 + c * 8;
                    *(bf16x8*)&kh[base] = hv;
                    *(bf16x8*)&kl[base] = lv;
                }
            }
        } else {
            for (int j = 0; j < 4; ++j) {
                int cid = t + j * 256;
                int d = cid >> 3, sc = cid & 7;
                bf16x8 hv;
                for (int q = 0; q < 8; ++q) {
                    unsigned w = Ep[(sc * 8 + q) * 132 + d];
                    hv[q] = (short)(w & 0xffffu);
                }
                int gr0 = m0 + p * 64 + sc * 8;
                int bb = gr0 >> 11, s0 = gr0 & 2047;
                *(bf16x8*)&vt[((size_t)bb * 128 + d) * 2048 + s0] = hv;
            }
        }
    }
}

// ---------------- flash attention (R9 structure, verified best) ----------------
// grid (S/128, B*H); 4 waves x 32 query rows (2 m-blocks); BN=64 keys/iter.
// K/V staged via global_load_lds with XOR-swizzled chunks between the two
// barriers (single drain point; wave-level overlap hides the rest).
// setprio(1) around MFMA clusters (kept from R9).
__global__ __launch_bounds__(256, 2) void attn_k(
    const short* __restrict__ qh, const short* __restrict__ ql,
    const short* __restrict__ kh, const short* __restrict__ kl,
    const short* __restrict__ vt, short* __restrict__ ctx) {
    constexpr int S = 2048, D = 128;
    __shared__ short Kh_s[64 * 128];    // swizzled, no pad
    __shared__ short Kl_s[64 * 128];
    __shared__ short Vt_s[128 * 64];    // swizzled, no pad
    __shared__ short P_s[128 * 72];     // per-wave 32-row slices, stride 64+8

    const int bh = blockIdx.y, b = bh >> 3, h = bh & 7;
    const int q0 = blockIdx.x * 128;
    const int t = threadIdx.x, wave = t >> 6, lane = t & 63;
    const int quad = lane >> 4, l16 = lane & 15;
    const int e8 = l16 & 7;             // xor-swizzle key

    // ones B-fragment: B[n=l16][k] = (n==0) ? 1.0bf16 : 0  -> C[., col0] = rowsum
    bf16x8 bones;
    {
        short o = (l16 == 0) ? (short)0x3F80 : (short)0;
        for (int j = 0; j < 8; ++j) bones[j] = o;
    }

    // Q fragments (A-layout A[m=l16][k=quad*8+j]), 2 m-blocks x 4 k-chunks
    bf16x8 qfh[2][4], qfl[2][4];
    for (int mb = 0; mb < 2; ++mb) {
        size_t qbase = ((size_t)(b * 8 + h) * S + q0 + wave * 32 + mb * 16 + l16) * D + quad * 8;
        for (int c = 0; c < 4; ++c) {
            qfh[mb][c] = *(const bf16x8*)(qh + qbase + c * 32);
            qfl[mb][c] = *(const bf16x8*)(ql + qbase + c * 32);
        }
    }

    float mrow[2][4];
    f32x4 oacc[2][8], lacc[2];
    for (int mb = 0; mb < 2; ++mb) {
        for (int r = 0; r < 4; ++r) mrow[mb][r] = -INFINITY;
        for (int oi = 0; oi < 8; ++oi) oacc[mb][oi] = (f32x4){0.f, 0.f, 0.f, 0.f};
        lacc[mb] = (f32x4){0.f, 0.f, 0.f, 0.f};
    }

    for (int kt = 0; kt < S / 64; ++kt) {
        __syncthreads();  // protect LDS reuse
        // --- stage K hi/lo: 64 rows x 128 ---
        {
            int pch = lane & 15;
            for (int i = 0; i < 4; ++i) {
                int rk = wave * 16 + i * 4 + (lane >> 4);
                int j = pch ^ (rk & 7);
                size_t g = ((size_t)b * S + kt * 64 + rk) * D + j * 8;
                int ldsoff = (wave * 16 + i * 4) * 128;
                __builtin_amdgcn_global_load_lds(GLB(kh + g), LDS(&Kh_s[ldsoff]), 16, 0, 0);
                __builtin_amdgcn_global_load_lds(GLB(kl + g), LDS(&Kl_s[ldsoff]), 16, 0, 0);
            }
        }
        // --- stage V^T: 128 rows(o) x 64(s) ---
        {
            int pch = lane & 7;
            for (int i = 0; i < 4; ++i) {
                int rv = wave * 32 + i * 8 + (lane >> 3);
                int j = pch ^ (rv & 7);
                size_t g = ((size_t)b * D + rv) * S + kt * 64 + j * 8;
                int ldsoff = (wave * 32 + i * 8) * 64;
                __builtin_amdgcn_global_load_lds(GLB(vt + g), LDS(&Vt_s[ldsoff]), 16, 0, 0);
            }
        }
        __syncthreads();

        // --- S' = Q' K^T (split: hh + lh + hl); scores already * scale*log2e ---
        f32x4 sacc[2][4];
        for (int mb = 0; mb < 2; ++mb)
            for (int ni = 0; ni < 4; ++ni) sacc[mb][ni] = (f32x4){0.f, 0.f, 0.f, 0.f};
        for (int ni = 0; ni < 4; ++ni) {
            for (int c = 0; c < 4; ++c) {
                int off = (ni * 16 + l16) * 128 + ((c * 4 + quad) ^ e8) * 8;
                bf16x8 kbh = *(const bf16x8*)&Kh_s[off];
                bf16x8 kbl = *(const bf16x8*)&Kl_s[off];
                __builtin_amdgcn_s_setprio(1);
                for (int mb = 0; mb < 2; ++mb) {
                    sacc[mb][ni] = MFMA(qfh[mb][c], kbh, sacc[mb][ni]);
                    sacc[mb][ni] = MFMA(qfl[mb][c], kbh, sacc[mb][ni]);
                    sacc[mb][ni] = MFMA(qfh[mb][c], kbl, sacc[mb][ni]);
                }
                __builtin_amdgcn_s_setprio(0);
            }
        }

        // --- online softmax (exp2 domain); rows quad*4+r per m-block ---
        for (int mb = 0; mb < 2; ++mb) {
            for (int r = 0; r < 4; ++r) {
                float mx = fmaxf(fmaxf(sacc[mb][0][r], sacc[mb][1][r]),
                                 fmaxf(sacc[mb][2][r], sacc[mb][3][r]));
                for (int off = 8; off; off >>= 1) mx = fmaxf(mx, __shfl_xor(mx, off));
                float mnew = fmaxf(mrow[mb][r], mx);
                float alpha = EXP2F(mrow[mb][r] - mnew);
                mrow[mb][r] = mnew;
                for (int ni = 0; ni < 4; ++ni)
                    sacc[mb][ni][r] = EXP2F(sacc[mb][ni][r] - mnew);
                lacc[mb][r] *= alpha;
                for (int oi = 0; oi < 8; ++oi) oacc[mb][oi][r] *= alpha;
            }
            // P -> LDS (C-layout -> A-layout); round-half-up bf16 (2 ops)
            for (int ni = 0; ni < 4; ++ni)
                for (int r = 0; r < 4; ++r) {
                    union { float f; unsigned u; } cv; cv.f = sacc[mb][ni][r];
                    P_s[(wave * 32 + mb * 16 + quad * 4 + r) * 72 + ni * 16 + l16] =
                        (short)((cv.u + 0x8000u) >> 16);
                }
        }

        // --- O += P @ V ; l += P @ ones (MFMA) ---
        for (int c2 = 0; c2 < 2; ++c2) {
            bf16x8 pa[2];
            for (int mb = 0; mb < 2; ++mb) {
                pa[mb] = *(const bf16x8*)&P_s[(wave * 32 + mb * 16 + l16) * 72 + c2 * 32 + quad * 8];
                lacc[mb] = MFMA(pa[mb], bones, lacc[mb]);
            }
            for (int oi = 0; oi < 8; ++oi) {
                int off = (oi * 16 + l16) * 64 + ((c2 * 4 + quad) ^ e8) * 8;
                bf16x8 vb = *(const bf16x8*)&Vt_s[off];
                __builtin_amdgcn_s_setprio(1);
                for (int mb = 0; mb < 2; ++mb)
                    oacc[mb][oi] = MFMA(pa[mb], vb, oacc[mb][oi]);
                __builtin_amdgcn_s_setprio(0);
            }
        }
    }

    // epilogue: ctx[b][s][h*128+o] bf16; l lives in col-0 lanes (l16==0)
    for (int mb = 0; mb < 2; ++mb) {
        for (int r = 0; r < 4; ++r) {
            float ls = __shfl(lacc[mb][r], lane & 48);  // broadcast from l16==0 of quad
            float inv = 1.f / ls;
            int s = q0 + wave * 32 + mb * 16 + quad * 4 + r;
            size_t base = ((size_t)b * S + s) * 1024 + h * 128;
            for (int oi = 0; oi < 8; ++oi)
                ctx[base + oi * 16 + l16] = f2bf(oacc[mb][oi][r] * inv);
        }
    }
}

// ---------------- launch ----------------

extern "C" void kernel_launch(void* const* d_in, const int* in_sizes, int n_in,
                              void* d_out, int out_size, void* d_ws, size_t ws_size,
                              hipStream_t stream) {
    const float* x  = (const float*)d_in[0];
    const float* Wq = (const float*)d_in[1];
    const float* Wk = (const float*)d_in[2];
    const float* Wv = (const float*)d_in[3];
    const float* Wo = (const float*)d_in[4];
    float* out = (float*)d_out;

    char* p = (char*)d_ws;
    auto alloc = [&](size_t bytes) { char* r = p; p += bytes; return r; };
    short* xh  = (short*)alloc(16777216);  // x hi    (8192 x 1024)
    short* xl  = (short*)alloc(16777216);  // x lo
    short* wth = (short*)alloc(2621440);   // Wt hi   (1280 x 1024)
    short* wtl = (short*)alloc(2621440);   // Wt lo
    short* wot = (short*)alloc(2097152);   // Wo^T    (1024 x 1024)
    short* qh  = (short*)alloc(16777216);  // Q hi    (B,H,S,D), pre-scaled
    short* ql  = (short*)alloc(16777216);  // Q lo
    short* kh  = (short*)alloc(2097152);   // K hi    (B,S,D)
    short* kl  = (short*)alloc(2097152);   // K lo
    short* vt  = (short*)alloc(2097152);   // V^T     (B,D,S)
    short* ctx = (short*)alloc(16777216);  // ctx     (B,S,H*D)

    prep_all<<<dim3(4352), dim3(256), 0, stream>>>(x, xh, xl, Wq, Wk, Wv,
                                                   wth, wtl, Wo, wot);
    gemm_k<0><<<dim3(64, 10), dim3(256), 0, stream>>>(xh, xl, wth, wtl,
                                                      qh, ql, kh, kl, vt, nullptr);
    attn_k<<<dim3(16, 32), dim3(256), 0, stream>>>(qh, ql, kh, kl, vt, ctx);
    gemm_k<1><<<dim3(64, 8), dim3(256), 0, stream>>>(ctx, nullptr, wot, nullptr,
                                                     nullptr, nullptr, nullptr, nullptr,
                                                     nullptr, out);
}